// Round 4
// baseline (574.770 us; speedup 1.0000x reference)
//
#include <hip/hip_runtime.h>

// Problem constants (from reference)
#define NN 100000
#define NE 1600000
#define NBUCKET 391   // ceil(NN / 256)
#define CHUNK 4096    // edges per block in p2 scatter

typedef __attribute__((ext_vector_type(2))) float v2f;

// ---------------- fp8 (OCP e4m3) helpers — storage only, math in fp32 ------

__device__ __forceinline__ unsigned int pk4fp8(float a, float b, float c, float d) {
    int t = __builtin_amdgcn_cvt_pk_fp8_f32(a, b, 0, false);   // bytes 0,1
    t = __builtin_amdgcn_cvt_pk_fp8_f32(c, d, t, true);        // bytes 2,3
    return (unsigned int)t;
}
// accumulate 4 fp8 (one uint) into a[0..3]
__device__ __forceinline__ void acc4(unsigned int u, float* a) {
    v2f p0 = __builtin_amdgcn_cvt_pk_f32_fp8((int)u, false);
    v2f p1 = __builtin_amdgcn_cvt_pk_f32_fp8((int)u, true);
    a[0] += p0.x; a[1] += p0.y; a[2] += p1.x; a[3] += p1.y;
}
__device__ __forceinline__ void acc16(uint4 u, float* a) {
    acc4(u.x, a); acc4(u.y, a + 4); acc4(u.z, a + 8); acc4(u.w, a + 12);
}

// ---------------- bf16 helpers (for the h2s intermediate) -------------------

__device__ __forceinline__ unsigned short f2b(float f) {
    unsigned int u; __builtin_memcpy(&u, &f, 4);
    unsigned int r = (u + 0x7fffu + ((u >> 16) & 1u)) >> 16;  // RNE
    return (unsigned short)r;
}
__device__ __forceinline__ unsigned int pk2b(float a, float b) {
    return (unsigned int)f2b(a) | ((unsigned int)f2b(b) << 16);
}
__device__ __forceinline__ float lo2f(unsigned int u) {
    unsigned int v = u << 16; float f; __builtin_memcpy(&f, &v, 4); return f;
}
__device__ __forceinline__ float hi2f(unsigned int u) {
    unsigned int v = u & 0xffff0000u; float f; __builtin_memcpy(&f, &v, 4); return f;
}

// ---------------- CSR build via bucketed counting sort ----------------------

__global__ void k_zero32(int* __restrict__ p, int n) {
    int i = blockIdx.x * 256 + threadIdx.x;
    if (i < n) p[i] = 0;
}

__global__ __launch_bounds__(256) void k_p1(const int* __restrict__ dst,
                                            int* __restrict__ bcnt, int E) {
    __shared__ int h[NBUCKET];
    for (int i = threadIdx.x; i < NBUCKET; i += 256) h[i] = 0;
    __syncthreads();
    int stride = gridDim.x * 256;
    for (int i = blockIdx.x * 256 + threadIdx.x; i < E; i += stride)
        atomicAdd(&h[dst[i] >> 8], 1);
    __syncthreads();
    for (int i = threadIdx.x; i < NBUCKET; i += 256)
        if (h[i]) atomicAdd(&bcnt[i], h[i]);
}

__global__ void k_scanb(const int* __restrict__ bcnt, int* __restrict__ bbase,
                        int* __restrict__ bfill) {
    __shared__ int s[512];
    int t = threadIdx.x;
    int v = (t < NBUCKET) ? bcnt[t] : 0;
    s[t] = v; __syncthreads();
    for (int off = 1; off < 512; off <<= 1) {
        int x = (t >= off) ? s[t - off] : 0;
        __syncthreads();
        s[t] += x;
        __syncthreads();
    }
    if (t < NBUCKET) { int ex = s[t] - v; bbase[t] = ex; bfill[t] = ex; }
    if (t == NBUCKET) bbase[t] = s[511];   // = E
}

__global__ __launch_bounds__(256) void k_p2(const int* __restrict__ src,
                                            const int* __restrict__ dst,
                                            int* __restrict__ bfill,
                                            unsigned int* __restrict__ entries, int E) {
    __shared__ int h[NBUCKET];
    __shared__ int cur[NBUCKET];
    int c0 = blockIdx.x * CHUNK;
    int c1 = min(E, c0 + CHUNK);
    for (int i = threadIdx.x; i < NBUCKET; i += 256) h[i] = 0;
    __syncthreads();
    for (int i = c0 + threadIdx.x; i < c1; i += 256) atomicAdd(&h[dst[i] >> 8], 1);
    __syncthreads();
    for (int i = threadIdx.x; i < NBUCKET; i += 256)
        cur[i] = h[i] ? atomicAdd(&bfill[i], h[i]) : 0;
    __syncthreads();
    for (int i = c0 + threadIdx.x; i < c1; i += 256) {
        int d = dst[i];
        int bkt = d >> 8;
        int pos = atomicAdd(&cur[bkt], 1);
        entries[pos] = (unsigned int)src[i] | ((unsigned int)(d & 255) << 17);
    }
}

// p4x: per-bucket histogram+scan -> row_ptr, dis, col; ALSO converts x -> fp8*dis
__global__ __launch_bounds__(256) void k_p4x(const unsigned int* __restrict__ entries,
                                             const int* __restrict__ bbase,
                                             int* __restrict__ row_ptr,
                                             float* __restrict__ dis,
                                             int* __restrict__ col,
                                             const float4* __restrict__ x4,
                                             uint2* __restrict__ xb2, int N) {
    __shared__ int cnt[256];
    __shared__ int cur[256];
    __shared__ int sc[256];
    __shared__ float sdis[256];
    int b = blockIdx.x;
    int e0 = bbase[b], e1 = bbase[b + 1];
    int t = threadIdx.x;
    cnt[t] = 0; __syncthreads();
    for (int i = e0 + t; i < e1; i += 256)
        atomicAdd(&cnt[(entries[i] >> 17) & 255], 1);
    __syncthreads();
    int v = cnt[t];
    sc[t] = v; __syncthreads();
    for (int off = 1; off < 256; off <<= 1) {
        int x = (t >= off) ? sc[t - off] : 0;
        __syncthreads();
        sc[t] += x;
        __syncthreads();
    }
    int ex = sc[t] - v;
    int n = (b << 8) + t;
    float dv = rsqrtf((float)(v + 1));
    if (n <= N) row_ptr[n] = e0 + ex;
    if (n < N) dis[n] = dv;
    sdis[t] = dv;
    cur[t] = e0 + ex;
    __syncthreads();
    for (int i = e0 + t; i < e1; i += 256) {
        unsigned int en = entries[i];
        int pos = atomicAdd(&cur[(en >> 17) & 255], 1);
        col[pos] = (int)(en & 0x1FFFF);
    }
    // x -> fp8 (scaled by dis), 256 nodes x 64 dims
    for (int idx = t; idx < 256 * 8; idx += 256) {
        int node = idx >> 3, k = idx & 7;
        int gn = (b << 8) + node;
        if (gn < N) {
            float s = sdis[node];
            float4 A = x4[gn * 16 + 2 * k];
            float4 B = x4[gn * 16 + 2 * k + 1];
            uint2 u;
            u.x = pk4fp8(A.x * s, A.y * s, A.z * s, A.w * s);
            u.y = pk4fp8(B.x * s, B.y * s, B.z * s, B.w * s);
            xb2[gn * 8 + k] = u;
        }
    }
}

// ---------------- fused layer kernels ----------------------------------------

// L1: aggregate xb (fp8, 64B rows, 16 edges in flight/wave) -> LDS, then
//     mm 64->128 (+b1, relu, *dis) -> h1 fp8
__global__ __launch_bounds__(256) void k_l1(
    const uint4* __restrict__ xb4, const int* __restrict__ row_ptr,
    const int* __restrict__ col, const float* __restrict__ dis,
    const float* __restrict__ W1, const float* __restrict__ b1,
    unsigned int* __restrict__ h1u, int N) {
    constexpr int STR = 68;
    __shared__ float At[64 * STR];
    const int tid = threadIdx.x;
    const int n0 = blockIdx.x * 64;
    const int lane = tid & 63, wave = tid >> 6;
    const int slot = lane >> 2, seg = lane & 3;
    // phase A: each wave aggregates 16 nodes (one at a time)
    for (int j = 0; j < 16; j++) {
        int nl = wave * 16 + j;
        int gn = n0 + nl;
        if (gn < N) {
            int b = row_ptr[gn], e = row_ptr[gn + 1];
            int items = e - b + 1;                 // item 0 = self
            float a[16];
            #pragma unroll
            for (int q = 0; q < 16; q++) a[q] = 0.f;
            for (int it = slot; it < items; it += 16) {
                int r = (it == 0) ? gn : col[b + it - 1];
                acc16(xb4[r * 4 + seg], a);
            }
            #pragma unroll
            for (int q = 0; q < 16; q++) {
                a[q] += __shfl_xor(a[q], 4);
                a[q] += __shfl_xor(a[q], 8);
                a[q] += __shfl_xor(a[q], 16);
                a[q] += __shfl_xor(a[q], 32);
            }
            if (slot == 0) {
                float s = dis[gn];
                #pragma unroll
                for (int q4 = 0; q4 < 4; q4++)
                    *(float4*)&At[nl * STR + seg * 16 + q4 * 4] =
                        make_float4(s * a[q4 * 4], s * a[q4 * 4 + 1],
                                    s * a[q4 * 4 + 2], s * a[q4 * 4 + 3]);
            }
        }
    }
    __syncthreads();
    // phase B: [64x64] @ W1[64x128]
    constexpr int CG = 32, NPT = 8;
    const int cg = tid % CG, ng = tid / CG, nb = ng * NPT;
    float acc[NPT][4];
    #pragma unroll
    for (int t = 0; t < NPT; t++) acc[t][0] = acc[t][1] = acc[t][2] = acc[t][3] = 0.f;
    const float4* W4 = (const float4*)W1;
    for (int k = 0; k < 64; k += 4) {
        float4 w0 = W4[(k + 0) * CG + cg];
        float4 w1 = W4[(k + 1) * CG + cg];
        float4 w2 = W4[(k + 2) * CG + cg];
        float4 w3 = W4[(k + 3) * CG + cg];
        #pragma unroll
        for (int t = 0; t < NPT; t++) {
            float4 a = *(const float4*)&At[(nb + t) * STR + k];
            acc[t][0] += a.x * w0.x; acc[t][1] += a.x * w0.y; acc[t][2] += a.x * w0.z; acc[t][3] += a.x * w0.w;
            acc[t][0] += a.y * w1.x; acc[t][1] += a.y * w1.y; acc[t][2] += a.y * w1.z; acc[t][3] += a.y * w1.w;
            acc[t][0] += a.z * w2.x; acc[t][1] += a.z * w2.y; acc[t][2] += a.z * w2.z; acc[t][3] += a.z * w2.w;
            acc[t][0] += a.w * w3.x; acc[t][1] += a.w * w3.y; acc[t][2] += a.w * w3.z; acc[t][3] += a.w * w3.w;
        }
    }
    float4 b4 = ((const float4*)b1)[cg];
    #pragma unroll
    for (int t = 0; t < NPT; t++) {
        int gn = n0 + nb + t;
        if (gn < N) {
            float s = dis[gn];
            float rx = fmaxf(acc[t][0] + b4.x, 0.f) * s;
            float ry = fmaxf(acc[t][1] + b4.y, 0.f) * s;
            float rz = fmaxf(acc[t][2] + b4.z, 0.f) * s;
            float rw = fmaxf(acc[t][3] + b4.w, 0.f) * s;
            h1u[gn * 32 + cg] = pk4fp8(rx, ry, rz, rw);
        }
    }
}

// L2: aggregate h1 (fp8, 128B rows, 8 edges in flight/wave) -> LDS, then
//     mm 128->128 (+b2, relu, *dis) -> h2s bf16
__global__ __launch_bounds__(256) void k_l2(
    const uint4* __restrict__ h1b4, const int* __restrict__ row_ptr,
    const int* __restrict__ col, const float* __restrict__ dis,
    const float* __restrict__ W2, const float* __restrict__ b2,
    uint2* __restrict__ h2b, int N) {
    constexpr int STR = 132;
    __shared__ float At[64 * STR];
    const int tid = threadIdx.x;
    const int n0 = blockIdx.x * 64;
    const int lane = tid & 63, wave = tid >> 6;
    const int slot = lane >> 3, seg = lane & 7;
    for (int j = 0; j < 16; j++) {
        int nl = wave * 16 + j;
        int gn = n0 + nl;
        if (gn < N) {
            int b = row_ptr[gn], e = row_ptr[gn + 1];
            int items = e - b + 1;
            float a[16];
            #pragma unroll
            for (int q = 0; q < 16; q++) a[q] = 0.f;
            for (int it = slot; it < items; it += 8) {
                int r = (it == 0) ? gn : col[b + it - 1];
                acc16(h1b4[r * 8 + seg], a);
            }
            #pragma unroll
            for (int q = 0; q < 16; q++) {
                a[q] += __shfl_xor(a[q], 8);
                a[q] += __shfl_xor(a[q], 16);
                a[q] += __shfl_xor(a[q], 32);
            }
            if (slot == 0) {
                float s = dis[gn];
                #pragma unroll
                for (int q4 = 0; q4 < 4; q4++)
                    *(float4*)&At[nl * STR + seg * 16 + q4 * 4] =
                        make_float4(s * a[q4 * 4], s * a[q4 * 4 + 1],
                                    s * a[q4 * 4 + 2], s * a[q4 * 4 + 3]);
            }
        }
    }
    __syncthreads();
    constexpr int CG = 32, NPT = 8;
    const int cg = tid % CG, ng = tid / CG, nb = ng * NPT;
    float acc[NPT][4];
    #pragma unroll
    for (int t = 0; t < NPT; t++) acc[t][0] = acc[t][1] = acc[t][2] = acc[t][3] = 0.f;
    const float4* W4 = (const float4*)W2;
    for (int k = 0; k < 128; k += 4) {
        float4 w0 = W4[(k + 0) * CG + cg];
        float4 w1 = W4[(k + 1) * CG + cg];
        float4 w2 = W4[(k + 2) * CG + cg];
        float4 w3 = W4[(k + 3) * CG + cg];
        #pragma unroll
        for (int t = 0; t < NPT; t++) {
            float4 a = *(const float4*)&At[(nb + t) * STR + k];
            acc[t][0] += a.x * w0.x; acc[t][1] += a.x * w0.y; acc[t][2] += a.x * w0.z; acc[t][3] += a.x * w0.w;
            acc[t][0] += a.y * w1.x; acc[t][1] += a.y * w1.y; acc[t][2] += a.y * w1.z; acc[t][3] += a.y * w1.w;
            acc[t][0] += a.z * w2.x; acc[t][1] += a.z * w2.y; acc[t][2] += a.z * w2.z; acc[t][3] += a.z * w2.w;
            acc[t][0] += a.w * w3.x; acc[t][1] += a.w * w3.y; acc[t][2] += a.w * w3.z; acc[t][3] += a.w * w3.w;
        }
    }
    float4 b4 = ((const float4*)b2)[cg];
    #pragma unroll
    for (int t = 0; t < NPT; t++) {
        int gn = n0 + nb + t;
        if (gn < N) {
            float s = dis[gn];
            float rx = fmaxf(acc[t][0] + b4.x, 0.f) * s;
            float ry = fmaxf(acc[t][1] + b4.y, 0.f) * s;
            float rz = fmaxf(acc[t][2] + b4.z, 0.f) * s;
            float rw = fmaxf(acc[t][3] + b4.w, 0.f) * s;
            uint2 u; u.x = pk2b(rx, ry); u.y = pk2b(rz, rw);
            h2b[gn * 32 + cg] = u;
        }
    }
}

// mm3: h2s (bf16) @ W3 [128->64] -> g3 fp8
__global__ __launch_bounds__(256) void k_mm3b(
    const uint2* __restrict__ h2b, const float* __restrict__ W3,
    unsigned int* __restrict__ g3u, int N) {
    constexpr int STR = 132;
    __shared__ float At[64 * STR];
    const int tid = threadIdx.x;
    const int n0 = blockIdx.x * 64;
    for (int idx = tid; idx < 64 * 32; idx += 256) {
        int node = idx >> 5, k8 = idx & 31;
        int gn = n0 + node;
        uint2 u = (gn < N) ? h2b[gn * 32 + k8] : make_uint2(0u, 0u);
        *(float4*)&At[node * STR + k8 * 4] =
            make_float4(lo2f(u.x), hi2f(u.x), lo2f(u.y), hi2f(u.y));
    }
    __syncthreads();
    constexpr int CG = 16, NPT = 4;
    const int cg = tid % CG, ng = tid / CG, nb = ng * NPT;
    float acc[NPT][4];
    #pragma unroll
    for (int t = 0; t < NPT; t++) acc[t][0] = acc[t][1] = acc[t][2] = acc[t][3] = 0.f;
    const float4* W4 = (const float4*)W3;
    for (int k = 0; k < 128; k += 4) {
        float4 w0 = W4[(k + 0) * CG + cg];
        float4 w1 = W4[(k + 1) * CG + cg];
        float4 w2 = W4[(k + 2) * CG + cg];
        float4 w3 = W4[(k + 3) * CG + cg];
        #pragma unroll
        for (int t = 0; t < NPT; t++) {
            float4 a = *(const float4*)&At[(nb + t) * STR + k];
            acc[t][0] += a.x * w0.x; acc[t][1] += a.x * w0.y; acc[t][2] += a.x * w0.z; acc[t][3] += a.x * w0.w;
            acc[t][0] += a.y * w1.x; acc[t][1] += a.y * w1.y; acc[t][2] += a.y * w1.z; acc[t][3] += a.y * w1.w;
            acc[t][0] += a.z * w2.x; acc[t][1] += a.z * w2.y; acc[t][2] += a.z * w2.z; acc[t][3] += a.z * w2.w;
            acc[t][0] += a.w * w3.x; acc[t][1] += a.w * w3.y; acc[t][2] += a.w * w3.z; acc[t][3] += a.w * w3.w;
        }
    }
    #pragma unroll
    for (int t = 0; t < NPT; t++) {
        int gn = n0 + nb + t;
        if (gn < N)
            g3u[gn * 16 + cg] = pk4fp8(acc[t][0], acc[t][1], acc[t][2], acc[t][3]);
    }
}

// L3 aggregate (fp8, 64B rows) + relu(+b3) + mean-pool partial reduction
__global__ __launch_bounds__(256) void k_aggpoolp(
    const uint4* __restrict__ g4, const int* __restrict__ row_ptr,
    const int* __restrict__ col, const float* __restrict__ dis,
    const float* __restrict__ b3, float* __restrict__ partial, int N) {
    int lane = threadIdx.x & 63, wib = threadIdx.x >> 6;
    int slot = lane >> 2, seg = lane & 3;
    float bl[16];
    #pragma unroll
    for (int j = 0; j < 16; j++) bl[j] = b3[seg * 16 + j];
    float ap[16];
    #pragma unroll
    for (int j = 0; j < 16; j++) ap[j] = 0.f;
    int gw = blockIdx.x * 4 + wib;
    for (int n = gw; n < N; n += 4096) {
        int b = row_ptr[n], e = row_ptr[n + 1];
        int items = e - b + 1;
        float a[16];
        #pragma unroll
        for (int j = 0; j < 16; j++) a[j] = 0.f;
        for (int it = slot; it < items; it += 16) {
            int r = (it == 0) ? n : col[b + it - 1];
            acc16(g4[r * 4 + seg], a);
        }
        #pragma unroll
        for (int j = 0; j < 16; j++) {
            a[j] += __shfl_xor(a[j], 4);
            a[j] += __shfl_xor(a[j], 8);
            a[j] += __shfl_xor(a[j], 16);
            a[j] += __shfl_xor(a[j], 32);
        }
        if (slot == 0) {
            float s = dis[n];
            #pragma unroll
            for (int j = 0; j < 16; j++) ap[j] += fmaxf(s * a[j] + bl[j], 0.f);
        }
    }
    __shared__ float red[4][64];
    if (slot == 0) {
        #pragma unroll
        for (int j = 0; j < 16; j++) red[wib][seg * 16 + j] = ap[j];
    }
    __syncthreads();
    int t = threadIdx.x;
    if (t < 64) {
        float r = red[0][t] + red[1][t] + red[2][t] + red[3][t];
        partial[blockIdx.x * 64 + t] = r;
    }
}

// reduce partials -> mean pool -> fc(relu) -> fc -> softmax -> out[2]
__global__ __launch_bounds__(256) void k_head(
    const float* __restrict__ partial, const float* __restrict__ Wc1,
    const float* __restrict__ bc1, const float* __restrict__ Wc2,
    const float* __restrict__ bc2, float* __restrict__ out, int NB, float invN) {
    __shared__ float red[256];
    __shared__ float pooled[64];
    __shared__ float z[32];
    __shared__ float lg[2];
    int t = threadIdx.x;
    int lane = t & 63, grp = t >> 6;
    float s = 0.f;
    for (int b = grp; b < NB; b += 4) s += partial[b * 64 + lane];
    red[t] = s; __syncthreads();
    if (t < 64) pooled[t] = (red[t] + red[t + 64] + red[t + 128] + red[t + 192]) * invN;
    __syncthreads();
    if (t < 32) {
        float a = bc1[t];
        for (int l = 0; l < 64; l++) a += pooled[l] * Wc1[l * 32 + t];
        z[t] = fmaxf(a, 0.f);
    }
    __syncthreads();
    if (t < 2) {
        float a = bc2[t];
        for (int j = 0; j < 32; j++) a += z[j] * Wc2[j * 2 + t];
        lg[t] = a;
    }
    __syncthreads();
    if (t == 0) {
        float m = fmaxf(lg[0], lg[1]);
        float e0 = __expf(lg[0] - m), e1 = __expf(lg[1] - m);
        float inv = 1.f / (e0 + e1);
        out[0] = e0 * inv;
        out[1] = e1 * inv;
    }
}

// ---------------- launch ----------------

extern "C" void kernel_launch(void* const* d_in, const int* in_sizes, int n_in,
                              void* d_out, int out_size, void* d_ws, size_t ws_size,
                              hipStream_t stream) {
    (void)in_sizes; (void)n_in; (void)out_size; (void)ws_size;
    const int N = NN, E = NE;

    const float* x   = (const float*)d_in[0];
    const int*   ei  = (const int*)d_in[1];
    const int*   srcp = ei;
    const int*   dstp = ei + E;
    const float* W1 = (const float*)d_in[2];
    const float* b1 = (const float*)d_in[3];
    const float* W2 = (const float*)d_in[4];
    const float* b2 = (const float*)d_in[5];
    const float* W3 = (const float*)d_in[6];
    const float* b3 = (const float*)d_in[7];
    const float* Wc1 = (const float*)d_in[8];
    const float* bc1 = (const float*)d_in[9];
    const float* Wc2 = (const float*)d_in[10];
    const float* bc2 = (const float*)d_in[11];
    float* out = (float*)d_out;

    char* base = (char*)d_ws;
    size_t off = 0;
    auto carve = [&](size_t bytes) -> char* {
        char* p = base + off;
        off = (off + bytes + 255) & ~(size_t)255;
        return p;
    };
    int*   bcnt    = (int*)carve((size_t)NBUCKET * 4);
    int*   bbase   = (int*)carve((size_t)(NBUCKET + 1) * 4);
    int*   bfill   = (int*)carve((size_t)NBUCKET * 4);
    int*   row_ptr = (int*)carve((size_t)(N + 1) * 4);
    int*   col     = (int*)carve((size_t)E * 4);
    float* dis     = (float*)carve((size_t)N * 4);
    float* partial = (float*)carve((size_t)1024 * 64 * 4);
    unsigned int* entries = (unsigned int*)carve((size_t)E * 4);
    unsigned int* xb      = (unsigned int*)carve((size_t)N * 64);       // fp8 [N,64]
    unsigned int* h1u     = (unsigned int*)carve((size_t)N * 128);      // fp8 [N,128]
    uint2*        h2b     = (uint2*)carve((size_t)N * 128 * 2);         // bf16 [N,128]
    unsigned int* g3u     = (unsigned int*)carve((size_t)N * 64);       // fp8 [N,64]

    // ---- CSR build + x->fp8 ----
    k_zero32<<<(NBUCKET + 255) / 256, 256, 0, stream>>>(bcnt, NBUCKET);
    k_p1<<<512, 256, 0, stream>>>(dstp, bcnt, E);
    k_scanb<<<1, 512, 0, stream>>>(bcnt, bbase, bfill);
    k_p2<<<(E + CHUNK - 1) / CHUNK, 256, 0, stream>>>(srcp, dstp, bfill, entries, E);
    k_p4x<<<NBUCKET, 256, 0, stream>>>(entries, bbase, row_ptr, dis, col,
                                       (const float4*)x, (uint2*)xb, N);

    const int NB64 = (N + 63) / 64;

    // ---- fused layers ----
    k_l1<<<NB64, 256, 0, stream>>>((const uint4*)xb, row_ptr, col, dis, W1, b1, h1u, N);
    k_l2<<<NB64, 256, 0, stream>>>((const uint4*)h1u, row_ptr, col, dis, W2, b2, h2b, N);
    k_mm3b<<<NB64, 256, 0, stream>>>(h2b, W3, g3u, N);
    k_aggpoolp<<<1024, 256, 0, stream>>>((const uint4*)g3u, row_ptr, col, dis, b3, partial, N);

    // ---- head ----
    k_head<<<1, 256, 0, stream>>>(partial, Wc1, bc1, Wc2, bc2, out, 1024, 1.0f / (float)N);
}

// Round 5
// 538.152 us; speedup vs baseline: 1.0680x; 1.0680x over previous
//
#include <hip/hip_runtime.h>

// Problem constants (from reference)
#define NN 100000
#define NE 1600000
#define NBUCKET 391   // ceil(NN / 256)
#define CHUNK 4096    // edges per block in p2 scatter

typedef __attribute__((ext_vector_type(2))) float v2f;

// ---------------- fp8 (OCP e4m3) helpers — storage only, math in fp32 ------

__device__ __forceinline__ unsigned int pk4fp8(float a, float b, float c, float d) {
    int t = __builtin_amdgcn_cvt_pk_fp8_f32(a, b, 0, false);   // bytes 0,1
    t = __builtin_amdgcn_cvt_pk_fp8_f32(c, d, t, true);        // bytes 2,3
    return (unsigned int)t;
}
__device__ __forceinline__ void acc4(unsigned int u, float* a) {
    v2f p0 = __builtin_amdgcn_cvt_pk_f32_fp8((int)u, false);
    v2f p1 = __builtin_amdgcn_cvt_pk_f32_fp8((int)u, true);
    a[0] += p0.x; a[1] += p0.y; a[2] += p1.x; a[3] += p1.y;
}
__device__ __forceinline__ void acc16(uint4 u, float* a) {
    acc4(u.x, a); acc4(u.y, a + 4); acc4(u.z, a + 8); acc4(u.w, a + 12);
}

// ---------------- bf16 helpers (for the h2s intermediate) -------------------

__device__ __forceinline__ unsigned short f2b(float f) {
    unsigned int u; __builtin_memcpy(&u, &f, 4);
    unsigned int r = (u + 0x7fffu + ((u >> 16) & 1u)) >> 16;  // RNE
    return (unsigned short)r;
}
__device__ __forceinline__ unsigned int pk2b(float a, float b) {
    return (unsigned int)f2b(a) | ((unsigned int)f2b(b) << 16);
}
__device__ __forceinline__ float lo2f(unsigned int u) {
    unsigned int v = u << 16; float f; __builtin_memcpy(&f, &v, 4); return f;
}
__device__ __forceinline__ float hi2f(unsigned int u) {
    unsigned int v = u & 0xffff0000u; float f; __builtin_memcpy(&f, &v, 4); return f;
}

// ---------------- CSR build via bucketed counting sort ----------------------

__global__ void k_zero32(int* __restrict__ p, int n) {
    int i = blockIdx.x * 256 + threadIdx.x;
    if (i < n) p[i] = 0;
}

__global__ __launch_bounds__(256) void k_p1(const int* __restrict__ dst,
                                            int* __restrict__ bcnt, int E) {
    __shared__ int h[NBUCKET];
    for (int i = threadIdx.x; i < NBUCKET; i += 256) h[i] = 0;
    __syncthreads();
    int stride = gridDim.x * 256;
    for (int i = blockIdx.x * 256 + threadIdx.x; i < E; i += stride)
        atomicAdd(&h[dst[i] >> 8], 1);
    __syncthreads();
    for (int i = threadIdx.x; i < NBUCKET; i += 256)
        if (h[i]) atomicAdd(&bcnt[i], h[i]);
}

__global__ void k_scanb(const int* __restrict__ bcnt, int* __restrict__ bbase,
                        int* __restrict__ bfill) {
    __shared__ int s[512];
    int t = threadIdx.x;
    int v = (t < NBUCKET) ? bcnt[t] : 0;
    s[t] = v; __syncthreads();
    for (int off = 1; off < 512; off <<= 1) {
        int x = (t >= off) ? s[t - off] : 0;
        __syncthreads();
        s[t] += x;
        __syncthreads();
    }
    if (t < NBUCKET) { int ex = s[t] - v; bbase[t] = ex; bfill[t] = ex; }
    if (t == NBUCKET) bbase[t] = s[511];   // = E
}

__global__ __launch_bounds__(256) void k_p2(const int* __restrict__ src,
                                            const int* __restrict__ dst,
                                            int* __restrict__ bfill,
                                            unsigned int* __restrict__ entries, int E) {
    __shared__ int h[NBUCKET];
    __shared__ int cur[NBUCKET];
    int c0 = blockIdx.x * CHUNK;
    int c1 = min(E, c0 + CHUNK);
    for (int i = threadIdx.x; i < NBUCKET; i += 256) h[i] = 0;
    __syncthreads();
    for (int i = c0 + threadIdx.x; i < c1; i += 256) atomicAdd(&h[dst[i] >> 8], 1);
    __syncthreads();
    for (int i = threadIdx.x; i < NBUCKET; i += 256)
        cur[i] = h[i] ? atomicAdd(&bfill[i], h[i]) : 0;
    __syncthreads();
    for (int i = c0 + threadIdx.x; i < c1; i += 256) {
        int d = dst[i];
        int bkt = d >> 8;
        int pos = atomicAdd(&cur[bkt], 1);
        entries[pos] = (unsigned int)src[i] | ((unsigned int)(d & 255) << 17);
    }
}

// p4x: per-bucket histogram+scan -> row_ptr, dis, col; ALSO converts x -> fp8*dis
__global__ __launch_bounds__(256) void k_p4x(const unsigned int* __restrict__ entries,
                                             const int* __restrict__ bbase,
                                             int* __restrict__ row_ptr,
                                             float* __restrict__ dis,
                                             int* __restrict__ col,
                                             const float4* __restrict__ x4,
                                             uint2* __restrict__ xb2, int N) {
    __shared__ int cnt[256];
    __shared__ int cur[256];
    __shared__ int sc[256];
    __shared__ float sdis[256];
    int b = blockIdx.x;
    int e0 = bbase[b], e1 = bbase[b + 1];
    int t = threadIdx.x;
    cnt[t] = 0; __syncthreads();
    for (int i = e0 + t; i < e1; i += 256)
        atomicAdd(&cnt[(entries[i] >> 17) & 255], 1);
    __syncthreads();
    int v = cnt[t];
    sc[t] = v; __syncthreads();
    for (int off = 1; off < 256; off <<= 1) {
        int x = (t >= off) ? sc[t - off] : 0;
        __syncthreads();
        sc[t] += x;
        __syncthreads();
    }
    int ex = sc[t] - v;
    int n = (b << 8) + t;
    float dv = rsqrtf((float)(v + 1));
    if (n <= N) row_ptr[n] = e0 + ex;
    if (n < N) dis[n] = dv;
    sdis[t] = dv;
    cur[t] = e0 + ex;
    __syncthreads();
    for (int i = e0 + t; i < e1; i += 256) {
        unsigned int en = entries[i];
        int pos = atomicAdd(&cur[(en >> 17) & 255], 1);
        col[pos] = (int)(en & 0x1FFFF);
    }
    // x -> fp8 (scaled by dis), 256 nodes x 64 dims
    for (int idx = t; idx < 256 * 8; idx += 256) {
        int node = idx >> 3, k = idx & 7;
        int gn = (b << 8) + node;
        if (gn < N) {
            float s = sdis[node];
            float4 A = x4[gn * 16 + 2 * k];
            float4 B = x4[gn * 16 + 2 * k + 1];
            uint2 u;
            u.x = pk4fp8(A.x * s, A.y * s, A.z * s, A.w * s);
            u.y = pk4fp8(B.x * s, B.y * s, B.z * s, B.w * s);
            xb2[gn * 8 + k] = u;
        }
    }
}

// ---------------- aggregation kernels (wave-per-node, no barriers) ----------

// D=64 fp8 gather: 4 lanes x 16B per row -> 16 rows in flight per wave-load.
// out[n] = dis[n] * (self + sum_in g[src]),  fp32 out [N,64]
__global__ __launch_bounds__(256) void k_agg64p(
    const uint4* __restrict__ g4, const int* __restrict__ row_ptr,
    const int* __restrict__ col, const float* __restrict__ dis,
    float* __restrict__ out, int N) {
    int w = blockIdx.x * 4 + (threadIdx.x >> 6);
    if (w >= N) return;
    int lane = threadIdx.x & 63;
    int slot = lane >> 2, seg = lane & 3;
    int b = row_ptr[w], e = row_ptr[w + 1];
    int items = e - b + 1;                    // item 0 = self
    float a[16];
    #pragma unroll
    for (int q = 0; q < 16; q++) a[q] = 0.f;
    for (int it = slot; it < items; it += 16) {
        int r = (it == 0) ? w : col[b + it - 1];
        acc16(g4[r * 4 + seg], a);
    }
    #pragma unroll
    for (int q = 0; q < 16; q++) {
        a[q] += __shfl_xor(a[q], 4);
        a[q] += __shfl_xor(a[q], 8);
        a[q] += __shfl_xor(a[q], 16);
        a[q] += __shfl_xor(a[q], 32);
    }
    if (slot == 0) {
        float s = dis[w];
        float4* o = (float4*)(out + w * 64 + seg * 16);
        #pragma unroll
        for (int q4 = 0; q4 < 4; q4++)
            o[q4] = make_float4(s * a[q4 * 4], s * a[q4 * 4 + 1],
                                s * a[q4 * 4 + 2], s * a[q4 * 4 + 3]);
    }
}

// D=128 fp8 gather: 8 lanes x 16B per row -> 8 rows in flight. fp32 out [N,128]
__global__ __launch_bounds__(256) void k_agg128p(
    const uint4* __restrict__ g4, const int* __restrict__ row_ptr,
    const int* __restrict__ col, const float* __restrict__ dis,
    float* __restrict__ out, int N) {
    int w = blockIdx.x * 4 + (threadIdx.x >> 6);
    if (w >= N) return;
    int lane = threadIdx.x & 63;
    int slot = lane >> 3, seg = lane & 7;
    int b = row_ptr[w], e = row_ptr[w + 1];
    int items = e - b + 1;
    float a[16];
    #pragma unroll
    for (int q = 0; q < 16; q++) a[q] = 0.f;
    for (int it = slot; it < items; it += 8) {
        int r = (it == 0) ? w : col[b + it - 1];
        acc16(g4[r * 8 + seg], a);
    }
    #pragma unroll
    for (int q = 0; q < 16; q++) {
        a[q] += __shfl_xor(a[q], 8);
        a[q] += __shfl_xor(a[q], 16);
        a[q] += __shfl_xor(a[q], 32);
    }
    if (slot == 0) {
        float s = dis[w];
        float4* o = (float4*)(out + w * 128 + seg * 16);
        #pragma unroll
        for (int q4 = 0; q4 < 4; q4++)
            o[q4] = make_float4(s * a[q4 * 4], s * a[q4 * 4 + 1],
                                s * a[q4 * 4 + 2], s * a[q4 * 4 + 3]);
    }
}

// ---------------- dense matmuls ----------------------------------------------

// out = A[N,Din] @ W[Din,Dout]; optional (+bias, relu), (*dis); OUTM 0=f32 1=bf16 2=fp8
template <int Din, int Dout, bool BR, bool SCALE, int OUTM>
__global__ __launch_bounds__(256) void k_mm(
    const float* __restrict__ A, const float* __restrict__ W,
    const float* __restrict__ bias, const float* __restrict__ dis,
    void* __restrict__ outv, int N) {
    constexpr int CG = Dout / 4;
    constexpr int NG = 256 / CG;
    constexpr int NPT = 64 / NG;
    constexpr int STR = Din + 4;
    constexpr int K4 = Din / 4;
    __shared__ float At[64 * STR];
    const int tid = threadIdx.x;
    const int n0 = blockIdx.x * 64;
    for (int idx = tid; idx < 64 * K4; idx += 256) {
        int node = idx / K4, k4 = idx % K4;
        int gn = n0 + node;
        float4 v = (gn < N) ? ((const float4*)A)[gn * K4 + k4]
                            : make_float4(0.f, 0.f, 0.f, 0.f);
        *(float4*)&At[node * STR + 4 * k4] = v;
    }
    __syncthreads();
    const int cg = tid % CG, ng = tid / CG, nb = ng * NPT;
    float acc[NPT][4];
    #pragma unroll
    for (int t = 0; t < NPT; t++) acc[t][0] = acc[t][1] = acc[t][2] = acc[t][3] = 0.f;
    const float4* W4 = (const float4*)W;
    for (int k = 0; k < Din; k += 4) {
        float4 w0 = W4[(k + 0) * CG + cg];
        float4 w1 = W4[(k + 1) * CG + cg];
        float4 w2 = W4[(k + 2) * CG + cg];
        float4 w3 = W4[(k + 3) * CG + cg];
        #pragma unroll
        for (int t = 0; t < NPT; t++) {
            float4 a = *(const float4*)&At[(nb + t) * STR + k];
            acc[t][0] += a.x * w0.x; acc[t][1] += a.x * w0.y; acc[t][2] += a.x * w0.z; acc[t][3] += a.x * w0.w;
            acc[t][0] += a.y * w1.x; acc[t][1] += a.y * w1.y; acc[t][2] += a.y * w1.z; acc[t][3] += a.y * w1.w;
            acc[t][0] += a.z * w2.x; acc[t][1] += a.z * w2.y; acc[t][2] += a.z * w2.z; acc[t][3] += a.z * w2.w;
            acc[t][0] += a.w * w3.x; acc[t][1] += a.w * w3.y; acc[t][2] += a.w * w3.z; acc[t][3] += a.w * w3.w;
        }
    }
    float4 b4 = BR ? ((const float4*)bias)[cg] : make_float4(0.f, 0.f, 0.f, 0.f);
    #pragma unroll
    for (int t = 0; t < NPT; t++) {
        int gn = n0 + nb + t;
        if (gn < N) {
            float rx = acc[t][0] + b4.x, ry = acc[t][1] + b4.y;
            float rz = acc[t][2] + b4.z, rw = acc[t][3] + b4.w;
            if (BR) {
                rx = fmaxf(rx, 0.f); ry = fmaxf(ry, 0.f);
                rz = fmaxf(rz, 0.f); rw = fmaxf(rw, 0.f);
            }
            if (SCALE) { float s = dis[gn]; rx *= s; ry *= s; rz *= s; rw *= s; }
            if (OUTM == 0) {
                ((float4*)outv)[gn * CG + cg] = make_float4(rx, ry, rz, rw);
            } else if (OUTM == 1) {
                uint2 u; u.x = pk2b(rx, ry); u.y = pk2b(rz, rw);
                ((uint2*)outv)[gn * CG + cg] = u;
            } else {
                ((unsigned int*)outv)[gn * CG + cg] = pk4fp8(rx, ry, rz, rw);
            }
        }
    }
}

// mm3: h2s (bf16 in) @ W3 [128->64] -> g3 fp8
__global__ __launch_bounds__(256) void k_mm3b(
    const uint2* __restrict__ h2b, const float* __restrict__ W3,
    unsigned int* __restrict__ g3u, int N) {
    constexpr int STR = 132;
    __shared__ float At[64 * STR];
    const int tid = threadIdx.x;
    const int n0 = blockIdx.x * 64;
    for (int idx = tid; idx < 64 * 32; idx += 256) {
        int node = idx >> 5, k8 = idx & 31;
        int gn = n0 + node;
        uint2 u = (gn < N) ? h2b[gn * 32 + k8] : make_uint2(0u, 0u);
        *(float4*)&At[node * STR + k8 * 4] =
            make_float4(lo2f(u.x), hi2f(u.x), lo2f(u.y), hi2f(u.y));
    }
    __syncthreads();
    constexpr int CG = 16, NPT = 4;
    const int cg = tid % CG, ng = tid / CG, nb = ng * NPT;
    float acc[NPT][4];
    #pragma unroll
    for (int t = 0; t < NPT; t++) acc[t][0] = acc[t][1] = acc[t][2] = acc[t][3] = 0.f;
    const float4* W4 = (const float4*)W3;
    for (int k = 0; k < 128; k += 4) {
        float4 w0 = W4[(k + 0) * CG + cg];
        float4 w1 = W4[(k + 1) * CG + cg];
        float4 w2 = W4[(k + 2) * CG + cg];
        float4 w3 = W4[(k + 3) * CG + cg];
        #pragma unroll
        for (int t = 0; t < NPT; t++) {
            float4 a = *(const float4*)&At[(nb + t) * STR + k];
            acc[t][0] += a.x * w0.x; acc[t][1] += a.x * w0.y; acc[t][2] += a.x * w0.z; acc[t][3] += a.x * w0.w;
            acc[t][0] += a.y * w1.x; acc[t][1] += a.y * w1.y; acc[t][2] += a.y * w1.z; acc[t][3] += a.y * w1.w;
            acc[t][0] += a.z * w2.x; acc[t][1] += a.z * w2.y; acc[t][2] += a.z * w2.z; acc[t][3] += a.z * w2.w;
            acc[t][0] += a.w * w3.x; acc[t][1] += a.w * w3.y; acc[t][2] += a.w * w3.z; acc[t][3] += a.w * w3.w;
        }
    }
    #pragma unroll
    for (int t = 0; t < NPT; t++) {
        int gn = n0 + nb + t;
        if (gn < N)
            g3u[gn * 16 + cg] = pk4fp8(acc[t][0], acc[t][1], acc[t][2], acc[t][3]);
    }
}

// L3 aggregate (fp8, 64B rows) + relu(+b3) + mean-pool partial reduction
__global__ __launch_bounds__(256) void k_aggpoolp(
    const uint4* __restrict__ g4, const int* __restrict__ row_ptr,
    const int* __restrict__ col, const float* __restrict__ dis,
    const float* __restrict__ b3, float* __restrict__ partial, int N) {
    int lane = threadIdx.x & 63, wib = threadIdx.x >> 6;
    int slot = lane >> 2, seg = lane & 3;
    float bl[16];
    #pragma unroll
    for (int j = 0; j < 16; j++) bl[j] = b3[seg * 16 + j];
    float ap[16];
    #pragma unroll
    for (int j = 0; j < 16; j++) ap[j] = 0.f;
    int gw = blockIdx.x * 4 + wib;
    for (int n = gw; n < N; n += 4096) {
        int b = row_ptr[n], e = row_ptr[n + 1];
        int items = e - b + 1;
        float a[16];
        #pragma unroll
        for (int j = 0; j < 16; j++) a[j] = 0.f;
        for (int it = slot; it < items; it += 16) {
            int r = (it == 0) ? n : col[b + it - 1];
            acc16(g4[r * 4 + seg], a);
        }
        #pragma unroll
        for (int j = 0; j < 16; j++) {
            a[j] += __shfl_xor(a[j], 4);
            a[j] += __shfl_xor(a[j], 8);
            a[j] += __shfl_xor(a[j], 16);
            a[j] += __shfl_xor(a[j], 32);
        }
        if (slot == 0) {
            float s = dis[n];
            #pragma unroll
            for (int j = 0; j < 16; j++) ap[j] += fmaxf(s * a[j] + bl[j], 0.f);
        }
    }
    __shared__ float red[4][64];
    if (slot == 0) {
        #pragma unroll
        for (int j = 0; j < 16; j++) red[wib][seg * 16 + j] = ap[j];
    }
    __syncthreads();
    int t = threadIdx.x;
    if (t < 64) {
        float r = red[0][t] + red[1][t] + red[2][t] + red[3][t];
        partial[blockIdx.x * 64 + t] = r;
    }
}

// reduce partials -> mean pool -> fc(relu) -> fc -> softmax -> out[2]
__global__ __launch_bounds__(256) void k_head(
    const float* __restrict__ partial, const float* __restrict__ Wc1,
    const float* __restrict__ bc1, const float* __restrict__ Wc2,
    const float* __restrict__ bc2, float* __restrict__ out, int NB, float invN) {
    __shared__ float red[256];
    __shared__ float pooled[64];
    __shared__ float z[32];
    __shared__ float lg[2];
    int t = threadIdx.x;
    int lane = t & 63, grp = t >> 6;
    float s = 0.f;
    for (int b = grp; b < NB; b += 4) s += partial[b * 64 + lane];
    red[t] = s; __syncthreads();
    if (t < 64) pooled[t] = (red[t] + red[t + 64] + red[t + 128] + red[t + 192]) * invN;
    __syncthreads();
    if (t < 32) {
        float a = bc1[t];
        for (int l = 0; l < 64; l++) a += pooled[l] * Wc1[l * 32 + t];
        z[t] = fmaxf(a, 0.f);
    }
    __syncthreads();
    if (t < 2) {
        float a = bc2[t];
        for (int j = 0; j < 32; j++) a += z[j] * Wc2[j * 2 + t];
        lg[t] = a;
    }
    __syncthreads();
    if (t == 0) {
        float m = fmaxf(lg[0], lg[1]);
        float e0 = __expf(lg[0] - m), e1 = __expf(lg[1] - m);
        float inv = 1.f / (e0 + e1);
        out[0] = e0 * inv;
        out[1] = e1 * inv;
    }
}

// ---------------- launch ----------------

extern "C" void kernel_launch(void* const* d_in, const int* in_sizes, int n_in,
                              void* d_out, int out_size, void* d_ws, size_t ws_size,
                              hipStream_t stream) {
    (void)in_sizes; (void)n_in; (void)out_size; (void)ws_size;
    const int N = NN, E = NE;

    const float* x   = (const float*)d_in[0];
    const int*   ei  = (const int*)d_in[1];
    const int*   srcp = ei;
    const int*   dstp = ei + E;
    const float* W1 = (const float*)d_in[2];
    const float* b1 = (const float*)d_in[3];
    const float* W2 = (const float*)d_in[4];
    const float* b2 = (const float*)d_in[5];
    const float* W3 = (const float*)d_in[6];
    const float* b3 = (const float*)d_in[7];
    const float* Wc1 = (const float*)d_in[8];
    const float* bc1 = (const float*)d_in[9];
    const float* Wc2 = (const float*)d_in[10];
    const float* bc2 = (const float*)d_in[11];
    float* out = (float*)d_out;

    char* base = (char*)d_ws;
    size_t off = 0;
    auto carve = [&](size_t bytes) -> char* {
        char* p = base + off;
        off = (off + bytes + 255) & ~(size_t)255;
        return p;
    };
    int*   bcnt    = (int*)carve((size_t)NBUCKET * 4);
    int*   bbase   = (int*)carve((size_t)(NBUCKET + 1) * 4);
    int*   bfill   = (int*)carve((size_t)NBUCKET * 4);
    int*   row_ptr = (int*)carve((size_t)(N + 1) * 4);
    int*   col     = (int*)carve((size_t)E * 4);
    float* dis     = (float*)carve((size_t)N * 4);
    float* partial = (float*)carve((size_t)1024 * 64 * 4);
    unsigned int* entries = (unsigned int*)carve((size_t)E * 4);
    unsigned int* xb      = (unsigned int*)carve((size_t)N * 64);   // fp8 [N,64]
    unsigned int* h1u     = (unsigned int*)carve((size_t)N * 128);  // fp8 [N,128]
    uint2*        h2b     = (uint2*)carve((size_t)N * 128 * 2);     // bf16 [N,128]
    unsigned int* g3u     = (unsigned int*)carve((size_t)N * 64);   // fp8 [N,64]
    float*        bufA    = (float*)carve((size_t)N * 128 * 4);     // fp32 agg out

    // ---- CSR build + x->fp8 ----
    k_zero32<<<(NBUCKET + 255) / 256, 256, 0, stream>>>(bcnt, NBUCKET);
    k_p1<<<512, 256, 0, stream>>>(dstp, bcnt, E);
    k_scanb<<<1, 512, 0, stream>>>(bcnt, bbase, bfill);
    k_p2<<<(E + CHUNK - 1) / CHUNK, 256, 0, stream>>>(srcp, dstp, bfill, entries, E);
    k_p4x<<<NBUCKET, 256, 0, stream>>>(entries, bbase, row_ptr, dis, col,
                                       (const float4*)x, (uint2*)xb, N);

    const int NBW = (N + 3) / 4;       // wave-per-node grids
    const int NB64 = (N + 63) / 64;

    // ---- layer 1: aggregate xb (fp8) -> fp32, mm 64->128 -> h1 fp8 ----
    k_agg64p<<<NBW, 256, 0, stream>>>((const uint4*)xb, row_ptr, col, dis, bufA, N);
    k_mm<64, 128, true, true, 2><<<NB64, 256, 0, stream>>>(bufA, W1, b1, dis, h1u, N);

    // ---- layer 2: aggregate h1 (fp8) -> fp32, mm 128->128 -> h2s bf16 ----
    k_agg128p<<<NBW, 256, 0, stream>>>((const uint4*)h1u, row_ptr, col, dis, bufA, N);
    k_mm<128, 128, true, true, 1><<<NB64, 256, 0, stream>>>(bufA, W2, b2, dis, h2b, N);

    // ---- layer 3: mm 128->64 -> g3 fp8, then aggregate+relu+pool (fused) ----
    k_mm3b<<<NB64, 256, 0, stream>>>(h2b, W3, g3u, N);
    k_aggpoolp<<<1024, 256, 0, stream>>>((const uint4*)g3u, row_ptr, col, dis, b3, partial, N);

    // ---- head ----
    k_head<<<1, 256, 0, stream>>>(partial, Wc1, bc1, Wc2, bc2, out, 1024, 1.0f / (float)N);
}

// Round 6
// 471.156 us; speedup vs baseline: 1.2199x; 1.1422x over previous
//
#include <hip/hip_runtime.h>

// Problem constants (from reference)
#define NN 100000
#define NE 1600000
#define NBUCKET 391   // ceil(NN / 256)
#define CHUNK 4096    // edges per block in p2 scatter

typedef __attribute__((ext_vector_type(2))) float v2f;

// ---------------- fp8 (OCP e4m3) helpers — storage only, math in fp32 ------

__device__ __forceinline__ unsigned int pk4fp8(float a, float b, float c, float d) {
    int t = __builtin_amdgcn_cvt_pk_fp8_f32(a, b, 0, false);   // bytes 0,1
    t = __builtin_amdgcn_cvt_pk_fp8_f32(c, d, t, true);        // bytes 2,3
    return (unsigned int)t;
}
__device__ __forceinline__ void acc4(unsigned int u, float* a) {
    v2f p0 = __builtin_amdgcn_cvt_pk_f32_fp8((int)u, false);
    v2f p1 = __builtin_amdgcn_cvt_pk_f32_fp8((int)u, true);
    a[0] += p0.x; a[1] += p0.y; a[2] += p1.x; a[3] += p1.y;
}
__device__ __forceinline__ void acc16(uint4 u, float* a) {
    acc4(u.x, a); acc4(u.y, a + 4); acc4(u.z, a + 8); acc4(u.w, a + 12);
}

// ---------------- bf16 helpers (for the h2s intermediate) -------------------

__device__ __forceinline__ unsigned short f2b(float f) {
    unsigned int u; __builtin_memcpy(&u, &f, 4);
    unsigned int r = (u + 0x7fffu + ((u >> 16) & 1u)) >> 16;  // RNE
    return (unsigned short)r;
}
__device__ __forceinline__ unsigned int pk2b(float a, float b) {
    return (unsigned int)f2b(a) | ((unsigned int)f2b(b) << 16);
}
__device__ __forceinline__ float lo2f(unsigned int u) {
    unsigned int v = u << 16; float f; __builtin_memcpy(&f, &v, 4); return f;
}
__device__ __forceinline__ float hi2f(unsigned int u) {
    unsigned int v = u & 0xffff0000u; float f; __builtin_memcpy(&f, &v, 4); return f;
}

// ---------------- CSR build via bucketed counting sort ----------------------

__global__ void k_zero32(int* __restrict__ p, int n) {
    int i = blockIdx.x * 256 + threadIdx.x;
    if (i < n) p[i] = 0;
}

__global__ __launch_bounds__(256) void k_p1(const int* __restrict__ dst,
                                            int* __restrict__ bcnt, int E) {
    __shared__ int h[NBUCKET];
    for (int i = threadIdx.x; i < NBUCKET; i += 256) h[i] = 0;
    __syncthreads();
    int stride = gridDim.x * 256;
    for (int i = blockIdx.x * 256 + threadIdx.x; i < E; i += stride)
        atomicAdd(&h[dst[i] >> 8], 1);
    __syncthreads();
    for (int i = threadIdx.x; i < NBUCKET; i += 256)
        if (h[i]) atomicAdd(&bcnt[i], h[i]);
}

__global__ void k_scanb(const int* __restrict__ bcnt, int* __restrict__ bbase,
                        int* __restrict__ bfill) {
    __shared__ int s[512];
    int t = threadIdx.x;
    int v = (t < NBUCKET) ? bcnt[t] : 0;
    s[t] = v; __syncthreads();
    for (int off = 1; off < 512; off <<= 1) {
        int x = (t >= off) ? s[t - off] : 0;
        __syncthreads();
        s[t] += x;
        __syncthreads();
    }
    if (t < NBUCKET) { int ex = s[t] - v; bbase[t] = ex; bfill[t] = ex; }
    if (t == NBUCKET) bbase[t] = s[511];   // = E
}

__global__ __launch_bounds__(256) void k_p2(const int* __restrict__ src,
                                            const int* __restrict__ dst,
                                            int* __restrict__ bfill,
                                            unsigned int* __restrict__ entries, int E) {
    __shared__ int h[NBUCKET];
    __shared__ int cur[NBUCKET];
    int c0 = blockIdx.x * CHUNK;
    int c1 = min(E, c0 + CHUNK);
    for (int i = threadIdx.x; i < NBUCKET; i += 256) h[i] = 0;
    __syncthreads();
    for (int i = c0 + threadIdx.x; i < c1; i += 256) atomicAdd(&h[dst[i] >> 8], 1);
    __syncthreads();
    for (int i = threadIdx.x; i < NBUCKET; i += 256)
        cur[i] = h[i] ? atomicAdd(&bfill[i], h[i]) : 0;
    __syncthreads();
    for (int i = c0 + threadIdx.x; i < c1; i += 256) {
        int d = dst[i];
        int bkt = d >> 8;
        int pos = atomicAdd(&cur[bkt], 1);
        entries[pos] = (unsigned int)src[i] | ((unsigned int)(d & 255) << 17);
    }
}

// p4x: per-bucket histogram+scan -> row_ptr, dis, col; ALSO converts x -> fp8*dis
__global__ __launch_bounds__(256) void k_p4x(const unsigned int* __restrict__ entries,
                                             const int* __restrict__ bbase,
                                             int* __restrict__ row_ptr,
                                             float* __restrict__ dis,
                                             int* __restrict__ col,
                                             const float4* __restrict__ x4,
                                             uint2* __restrict__ xb2, int N) {
    __shared__ int cnt[256];
    __shared__ int cur[256];
    __shared__ int sc[256];
    __shared__ float sdis[256];
    int b = blockIdx.x;
    int e0 = bbase[b], e1 = bbase[b + 1];
    int t = threadIdx.x;
    cnt[t] = 0; __syncthreads();
    for (int i = e0 + t; i < e1; i += 256)
        atomicAdd(&cnt[(entries[i] >> 17) & 255], 1);
    __syncthreads();
    int v = cnt[t];
    sc[t] = v; __syncthreads();
    for (int off = 1; off < 256; off <<= 1) {
        int x = (t >= off) ? sc[t - off] : 0;
        __syncthreads();
        sc[t] += x;
        __syncthreads();
    }
    int ex = sc[t] - v;
    int n = (b << 8) + t;
    float dv = rsqrtf((float)(v + 1));
    if (n <= N) row_ptr[n] = e0 + ex;
    if (n < N) dis[n] = dv;
    sdis[t] = dv;
    cur[t] = e0 + ex;
    __syncthreads();
    for (int i = e0 + t; i < e1; i += 256) {
        unsigned int en = entries[i];
        int pos = atomicAdd(&cur[(en >> 17) & 255], 1);
        col[pos] = (int)(en & 0x1FFFF);
    }
    // x -> fp8 (scaled by dis), 256 nodes x 64 dims
    for (int idx = t; idx < 256 * 8; idx += 256) {
        int node = idx >> 3, k = idx & 7;
        int gn = (b << 8) + node;
        if (gn < N) {
            float s = sdis[node];
            float4 A = x4[gn * 16 + 2 * k];
            float4 B = x4[gn * 16 + 2 * k + 1];
            uint2 u;
            u.x = pk4fp8(A.x * s, A.y * s, A.z * s, A.w * s);
            u.y = pk4fp8(B.x * s, B.y * s, B.z * s, B.w * s);
            xb2[gn * 8 + k] = u;
        }
    }
}

// ---------------- aggregation: slot-per-node, no shuffles -------------------

// D=64 fp8: 4-lane slot owns one node; lane holds 16 dims. 16 nodes per wave.
// out[n] = dis[n] * (self + sum_in g[src]),  fp32 out [N,64]
__global__ __launch_bounds__(256) void k_agg64s(
    const uint4* __restrict__ g4, const int* __restrict__ row_ptr,
    const int* __restrict__ col, const float* __restrict__ dis,
    float* __restrict__ out, int N) {
    int tid = threadIdx.x;
    int lane = tid & 63, wave = tid >> 6;
    int slot = lane >> 2, seg = lane & 3;
    int n = blockIdx.x * 64 + wave * 16 + slot;
    if (n >= N) return;
    int b = row_ptr[n], e = row_ptr[n + 1];
    float a[16];
    #pragma unroll
    for (int q = 0; q < 16; q++) a[q] = 0.f;
    acc16(g4[n * 4 + seg], a);                 // self-loop
    int i = b;
    for (; i + 4 <= e; i += 4) {
        int c0 = col[i], c1 = col[i + 1], c2 = col[i + 2], c3 = col[i + 3];
        uint4 u0 = g4[c0 * 4 + seg], u1 = g4[c1 * 4 + seg];
        uint4 u2 = g4[c2 * 4 + seg], u3 = g4[c3 * 4 + seg];
        acc16(u0, a); acc16(u1, a); acc16(u2, a); acc16(u3, a);
    }
    for (; i < e; i++) acc16(g4[col[i] * 4 + seg], a);
    float s = dis[n];
    float4* o = (float4*)(out + n * 64 + seg * 16);
    #pragma unroll
    for (int q4 = 0; q4 < 4; q4++)
        o[q4] = make_float4(s * a[q4 * 4], s * a[q4 * 4 + 1],
                            s * a[q4 * 4 + 2], s * a[q4 * 4 + 3]);
}

// D=128 fp8: 8-lane slot owns one node; lane holds 16 dims. 8 nodes per wave.
__global__ __launch_bounds__(256) void k_agg128s(
    const uint4* __restrict__ g4, const int* __restrict__ row_ptr,
    const int* __restrict__ col, const float* __restrict__ dis,
    float* __restrict__ out, int N) {
    int tid = threadIdx.x;
    int lane = tid & 63, wave = tid >> 6;
    int slot = lane >> 3, seg = lane & 7;
    int n = blockIdx.x * 32 + wave * 8 + slot;
    if (n >= N) return;
    int b = row_ptr[n], e = row_ptr[n + 1];
    float a[16];
    #pragma unroll
    for (int q = 0; q < 16; q++) a[q] = 0.f;
    acc16(g4[n * 8 + seg], a);                 // self-loop
    int i = b;
    for (; i + 4 <= e; i += 4) {
        int c0 = col[i], c1 = col[i + 1], c2 = col[i + 2], c3 = col[i + 3];
        uint4 u0 = g4[c0 * 8 + seg], u1 = g4[c1 * 8 + seg];
        uint4 u2 = g4[c2 * 8 + seg], u3 = g4[c3 * 8 + seg];
        acc16(u0, a); acc16(u1, a); acc16(u2, a); acc16(u3, a);
    }
    for (; i < e; i++) acc16(g4[col[i] * 8 + seg], a);
    float s = dis[n];
    float4* o = (float4*)(out + n * 128 + seg * 16);
    #pragma unroll
    for (int q4 = 0; q4 < 4; q4++)
        o[q4] = make_float4(s * a[q4 * 4], s * a[q4 * 4 + 1],
                            s * a[q4 * 4 + 2], s * a[q4 * 4 + 3]);
}

// L3: slot-per-node aggregate + relu(+b3) + pool. One shuffle tree per WAVE
// (amortized over 16 nodes), then block LDS reduce -> partial[block][64].
__global__ __launch_bounds__(256) void k_aggpools(
    const uint4* __restrict__ g4, const int* __restrict__ row_ptr,
    const int* __restrict__ col, const float* __restrict__ dis,
    const float* __restrict__ b3, float* __restrict__ partial, int N) {
    int tid = threadIdx.x;
    int lane = tid & 63, wave = tid >> 6;
    int slot = lane >> 2, seg = lane & 3;
    int n = blockIdx.x * 64 + wave * 16 + slot;
    float ap[16];
    #pragma unroll
    for (int j = 0; j < 16; j++) ap[j] = 0.f;
    if (n < N) {
        int b = row_ptr[n], e = row_ptr[n + 1];
        float a[16];
        #pragma unroll
        for (int q = 0; q < 16; q++) a[q] = 0.f;
        acc16(g4[n * 4 + seg], a);
        int i = b;
        for (; i + 4 <= e; i += 4) {
            int c0 = col[i], c1 = col[i + 1], c2 = col[i + 2], c3 = col[i + 3];
            uint4 u0 = g4[c0 * 4 + seg], u1 = g4[c1 * 4 + seg];
            uint4 u2 = g4[c2 * 4 + seg], u3 = g4[c3 * 4 + seg];
            acc16(u0, a); acc16(u1, a); acc16(u2, a); acc16(u3, a);
        }
        for (; i < e; i++) acc16(g4[col[i] * 4 + seg], a);
        float s = dis[n];
        #pragma unroll
        for (int j = 0; j < 16; j++)
            ap[j] = fmaxf(s * a[j] + b3[seg * 16 + j], 0.f);
    }
    // reduce across the 16 slots of this wave (lanes stride 4 hold same dims)
    #pragma unroll
    for (int j = 0; j < 16; j++) {
        ap[j] += __shfl_xor(ap[j], 4);
        ap[j] += __shfl_xor(ap[j], 8);
        ap[j] += __shfl_xor(ap[j], 16);
        ap[j] += __shfl_xor(ap[j], 32);
    }
    __shared__ float red[4][64];
    if (slot == 0) {
        #pragma unroll
        for (int j = 0; j < 16; j++) red[wave][seg * 16 + j] = ap[j];
    }
    __syncthreads();
    if (tid < 64)
        partial[blockIdx.x * 64 + tid] =
            red[0][tid] + red[1][tid] + red[2][tid] + red[3][tid];
}

// ---------------- dense matmuls ----------------------------------------------

// out = A[N,Din] @ W[Din,Dout]; optional (+bias, relu), (*dis); OUTM 0=f32 1=bf16 2=fp8
template <int Din, int Dout, bool BR, bool SCALE, int OUTM>
__global__ __launch_bounds__(256) void k_mm(
    const float* __restrict__ A, const float* __restrict__ W,
    const float* __restrict__ bias, const float* __restrict__ dis,
    void* __restrict__ outv, int N) {
    constexpr int CG = Dout / 4;
    constexpr int NG = 256 / CG;
    constexpr int NPT = 64 / NG;
    constexpr int STR = Din + 4;
    constexpr int K4 = Din / 4;
    __shared__ float At[64 * STR];
    const int tid = threadIdx.x;
    const int n0 = blockIdx.x * 64;
    for (int idx = tid; idx < 64 * K4; idx += 256) {
        int node = idx / K4, k4 = idx % K4;
        int gn = n0 + node;
        float4 v = (gn < N) ? ((const float4*)A)[gn * K4 + k4]
                            : make_float4(0.f, 0.f, 0.f, 0.f);
        *(float4*)&At[node * STR + 4 * k4] = v;
    }
    __syncthreads();
    const int cg = tid % CG, ng = tid / CG, nb = ng * NPT;
    float acc[NPT][4];
    #pragma unroll
    for (int t = 0; t < NPT; t++) acc[t][0] = acc[t][1] = acc[t][2] = acc[t][3] = 0.f;
    const float4* W4 = (const float4*)W;
    for (int k = 0; k < Din; k += 4) {
        float4 w0 = W4[(k + 0) * CG + cg];
        float4 w1 = W4[(k + 1) * CG + cg];
        float4 w2 = W4[(k + 2) * CG + cg];
        float4 w3 = W4[(k + 3) * CG + cg];
        #pragma unroll
        for (int t = 0; t < NPT; t++) {
            float4 a = *(const float4*)&At[(nb + t) * STR + k];
            acc[t][0] += a.x * w0.x; acc[t][1] += a.x * w0.y; acc[t][2] += a.x * w0.z; acc[t][3] += a.x * w0.w;
            acc[t][0] += a.y * w1.x; acc[t][1] += a.y * w1.y; acc[t][2] += a.y * w1.z; acc[t][3] += a.y * w1.w;
            acc[t][0] += a.z * w2.x; acc[t][1] += a.z * w2.y; acc[t][2] += a.z * w2.z; acc[t][3] += a.z * w2.w;
            acc[t][0] += a.w * w3.x; acc[t][1] += a.w * w3.y; acc[t][2] += a.w * w3.z; acc[t][3] += a.w * w3.w;
        }
    }
    float4 b4 = BR ? ((const float4*)bias)[cg] : make_float4(0.f, 0.f, 0.f, 0.f);
    #pragma unroll
    for (int t = 0; t < NPT; t++) {
        int gn = n0 + nb + t;
        if (gn < N) {
            float rx = acc[t][0] + b4.x, ry = acc[t][1] + b4.y;
            float rz = acc[t][2] + b4.z, rw = acc[t][3] + b4.w;
            if (BR) {
                rx = fmaxf(rx, 0.f); ry = fmaxf(ry, 0.f);
                rz = fmaxf(rz, 0.f); rw = fmaxf(rw, 0.f);
            }
            if (SCALE) { float s = dis[gn]; rx *= s; ry *= s; rz *= s; rw *= s; }
            if (OUTM == 0) {
                ((float4*)outv)[gn * CG + cg] = make_float4(rx, ry, rz, rw);
            } else if (OUTM == 1) {
                uint2 u; u.x = pk2b(rx, ry); u.y = pk2b(rz, rw);
                ((uint2*)outv)[gn * CG + cg] = u;
            } else {
                ((unsigned int*)outv)[gn * CG + cg] = pk4fp8(rx, ry, rz, rw);
            }
        }
    }
}

// mm3: h2s (bf16 in) @ W3 [128->64] -> g3 fp8
__global__ __launch_bounds__(256) void k_mm3b(
    const uint2* __restrict__ h2b, const float* __restrict__ W3,
    unsigned int* __restrict__ g3u, int N) {
    constexpr int STR = 132;
    __shared__ float At[64 * STR];
    const int tid = threadIdx.x;
    const int n0 = blockIdx.x * 64;
    for (int idx = tid; idx < 64 * 32; idx += 256) {
        int node = idx >> 5, k8 = idx & 31;
        int gn = n0 + node;
        uint2 u = (gn < N) ? h2b[gn * 32 + k8] : make_uint2(0u, 0u);
        *(float4*)&At[node * STR + k8 * 4] =
            make_float4(lo2f(u.x), hi2f(u.x), lo2f(u.y), hi2f(u.y));
    }
    __syncthreads();
    constexpr int CG = 16, NPT = 4;
    const int cg = tid % CG, ng = tid / CG, nb = ng * NPT;
    float acc[NPT][4];
    #pragma unroll
    for (int t = 0; t < NPT; t++) acc[t][0] = acc[t][1] = acc[t][2] = acc[t][3] = 0.f;
    const float4* W4 = (const float4*)W3;
    for (int k = 0; k < 128; k += 4) {
        float4 w0 = W4[(k + 0) * CG + cg];
        float4 w1 = W4[(k + 1) * CG + cg];
        float4 w2 = W4[(k + 2) * CG + cg];
        float4 w3 = W4[(k + 3) * CG + cg];
        #pragma unroll
        for (int t = 0; t < NPT; t++) {
            float4 a = *(const float4*)&At[(nb + t) * STR + k];
            acc[t][0] += a.x * w0.x; acc[t][1] += a.x * w0.y; acc[t][2] += a.x * w0.z; acc[t][3] += a.x * w0.w;
            acc[t][0] += a.y * w1.x; acc[t][1] += a.y * w1.y; acc[t][2] += a.y * w1.z; acc[t][3] += a.y * w1.w;
            acc[t][0] += a.z * w2.x; acc[t][1] += a.z * w2.y; acc[t][2] += a.z * w2.z; acc[t][3] += a.z * w2.w;
            acc[t][0] += a.w * w3.x; acc[t][1] += a.w * w3.y; acc[t][2] += a.w * w3.z; acc[t][3] += a.w * w3.w;
        }
    }
    #pragma unroll
    for (int t = 0; t < NPT; t++) {
        int gn = n0 + nb + t;
        if (gn < N)
            g3u[gn * 16 + cg] = pk4fp8(acc[t][0], acc[t][1], acc[t][2], acc[t][3]);
    }
}

// reduce partials -> mean pool -> fc(relu) -> fc -> softmax -> out[2]
__global__ __launch_bounds__(256) void k_head(
    const float* __restrict__ partial, const float* __restrict__ Wc1,
    const float* __restrict__ bc1, const float* __restrict__ Wc2,
    const float* __restrict__ bc2, float* __restrict__ out, int NB, float invN) {
    __shared__ float red[256];
    __shared__ float pooled[64];
    __shared__ float z[32];
    __shared__ float lg[2];
    int t = threadIdx.x;
    int lane = t & 63, grp = t >> 6;
    float s = 0.f;
    for (int b = grp; b < NB; b += 4) s += partial[b * 64 + lane];
    red[t] = s; __syncthreads();
    if (t < 64) pooled[t] = (red[t] + red[t + 64] + red[t + 128] + red[t + 192]) * invN;
    __syncthreads();
    if (t < 32) {
        float a = bc1[t];
        for (int l = 0; l < 64; l++) a += pooled[l] * Wc1[l * 32 + t];
        z[t] = fmaxf(a, 0.f);
    }
    __syncthreads();
    if (t < 2) {
        float a = bc2[t];
        for (int j = 0; j < 32; j++) a += z[j] * Wc2[j * 2 + t];
        lg[t] = a;
    }
    __syncthreads();
    if (t == 0) {
        float m = fmaxf(lg[0], lg[1]);
        float e0 = __expf(lg[0] - m), e1 = __expf(lg[1] - m);
        float inv = 1.f / (e0 + e1);
        out[0] = e0 * inv;
        out[1] = e1 * inv;
    }
}

// ---------------- launch ----------------

extern "C" void kernel_launch(void* const* d_in, const int* in_sizes, int n_in,
                              void* d_out, int out_size, void* d_ws, size_t ws_size,
                              hipStream_t stream) {
    (void)in_sizes; (void)n_in; (void)out_size; (void)ws_size;
    const int N = NN, E = NE;

    const float* x   = (const float*)d_in[0];
    const int*   ei  = (const int*)d_in[1];
    const int*   srcp = ei;
    const int*   dstp = ei + E;
    const float* W1 = (const float*)d_in[2];
    const float* b1 = (const float*)d_in[3];
    const float* W2 = (const float*)d_in[4];
    const float* b2 = (const float*)d_in[5];
    const float* W3 = (const float*)d_in[6];
    const float* b3 = (const float*)d_in[7];
    const float* Wc1 = (const float*)d_in[8];
    const float* bc1 = (const float*)d_in[9];
    const float* Wc2 = (const float*)d_in[10];
    const float* bc2 = (const float*)d_in[11];
    float* out = (float*)d_out;

    char* base = (char*)d_ws;
    size_t off = 0;
    auto carve = [&](size_t bytes) -> char* {
        char* p = base + off;
        off = (off + bytes + 255) & ~(size_t)255;
        return p;
    };
    int*   bcnt    = (int*)carve((size_t)NBUCKET * 4);
    int*   bbase   = (int*)carve((size_t)(NBUCKET + 1) * 4);
    int*   bfill   = (int*)carve((size_t)NBUCKET * 4);
    int*   row_ptr = (int*)carve((size_t)(N + 1) * 4);
    int*   col     = (int*)carve((size_t)E * 4);
    float* dis     = (float*)carve((size_t)N * 4);
    float* partial = (float*)carve((size_t)1600 * 64 * 4);
    unsigned int* entries = (unsigned int*)carve((size_t)E * 4);
    unsigned int* xb      = (unsigned int*)carve((size_t)N * 64);   // fp8 [N,64]
    unsigned int* h1u     = (unsigned int*)carve((size_t)N * 128);  // fp8 [N,128]
    uint2*        h2b     = (uint2*)carve((size_t)N * 128 * 2);     // bf16 [N,128]
    unsigned int* g3u     = (unsigned int*)carve((size_t)N * 64);   // fp8 [N,64]
    float*        bufA    = (float*)carve((size_t)N * 128 * 4);     // fp32 agg out

    // ---- CSR build + x->fp8 ----
    k_zero32<<<(NBUCKET + 255) / 256, 256, 0, stream>>>(bcnt, NBUCKET);
    k_p1<<<512, 256, 0, stream>>>(dstp, bcnt, E);
    k_scanb<<<1, 512, 0, stream>>>(bcnt, bbase, bfill);
    k_p2<<<(E + CHUNK - 1) / CHUNK, 256, 0, stream>>>(srcp, dstp, bfill, entries, E);
    k_p4x<<<NBUCKET, 256, 0, stream>>>(entries, bbase, row_ptr, dis, col,
                                       (const float4*)x, (uint2*)xb, N);

    const int NB64 = (N + 63) / 64;    // 1563 — slot-per-node D=64 & mm grids
    const int NB32 = (N + 31) / 32;    // 3125 — slot-per-node D=128 grid

    // ---- layer 1: aggregate xb (fp8) -> fp32, mm 64->128 -> h1 fp8 ----
    k_agg64s<<<NB64, 256, 0, stream>>>((const uint4*)xb, row_ptr, col, dis, bufA, N);
    k_mm<64, 128, true, true, 2><<<NB64, 256, 0, stream>>>(bufA, W1, b1, dis, h1u, N);

    // ---- layer 2: aggregate h1 (fp8) -> fp32, mm 128->128 -> h2s bf16 ----
    k_agg128s<<<NB32, 256, 0, stream>>>((const uint4*)h1u, row_ptr, col, dis, bufA, N);
    k_mm<128, 128, true, true, 1><<<NB64, 256, 0, stream>>>(bufA, W2, b2, dis, h2b, N);

    // ---- layer 3: mm 128->64 -> g3 fp8, then aggregate+relu+pool (fused) ----
    k_mm3b<<<NB64, 256, 0, stream>>>(h2b, W3, g3u, N);
    k_aggpools<<<NB64, 256, 0, stream>>>((const uint4*)g3u, row_ptr, col, dis, b3, partial, N);

    // ---- head ----
    k_head<<<1, 256, 0, stream>>>(partial, Wc1, bc1, Wc2, bc2, out, NB64, 1.0f / (float)N);
}

// Round 7
// 391.687 us; speedup vs baseline: 1.4674x; 1.2029x over previous
//
#include <hip/hip_runtime.h>

// Problem constants (from reference)
#define NN 100000
#define NE 1600000
#define NBUCKET 391   // ceil(NN / 256)
#define CHUNK 4096    // edges per block in p2 scatter

typedef __attribute__((ext_vector_type(2))) float v2f;

// ---------------- fp8 (OCP e4m3) helpers — storage only, math in fp32 ------

__device__ __forceinline__ unsigned int pk4fp8(float a, float b, float c, float d) {
    int t = __builtin_amdgcn_cvt_pk_fp8_f32(a, b, 0, false);   // bytes 0,1
    t = __builtin_amdgcn_cvt_pk_fp8_f32(c, d, t, true);        // bytes 2,3
    return (unsigned int)t;
}
__device__ __forceinline__ void acc4(unsigned int u, float* a) {
    v2f p0 = __builtin_amdgcn_cvt_pk_f32_fp8((int)u, false);
    v2f p1 = __builtin_amdgcn_cvt_pk_f32_fp8((int)u, true);
    a[0] += p0.x; a[1] += p0.y; a[2] += p1.x; a[3] += p1.y;
}
__device__ __forceinline__ void acc16(uint4 u, float* a) {
    acc4(u.x, a); acc4(u.y, a + 4); acc4(u.z, a + 8); acc4(u.w, a + 12);
}

// ---------------- bf16 helpers (for the h2s intermediate) -------------------

__device__ __forceinline__ unsigned short f2b(float f) {
    unsigned int u; __builtin_memcpy(&u, &f, 4);
    unsigned int r = (u + 0x7fffu + ((u >> 16) & 1u)) >> 16;  // RNE
    return (unsigned short)r;
}
__device__ __forceinline__ unsigned int pk2b(float a, float b) {
    return (unsigned int)f2b(a) | ((unsigned int)f2b(b) << 16);
}
__device__ __forceinline__ float lo2f(unsigned int u) {
    unsigned int v = u << 16; float f; __builtin_memcpy(&f, &v, 4); return f;
}
__device__ __forceinline__ float hi2f(unsigned int u) {
    unsigned int v = u & 0xffff0000u; float f; __builtin_memcpy(&f, &v, 4); return f;
}

// ---------------- CSR build via bucketed counting sort ----------------------

__global__ void k_zero32(int* __restrict__ p, int n) {
    int i = blockIdx.x * 256 + threadIdx.x;
    if (i < n) p[i] = 0;
}

__global__ __launch_bounds__(256) void k_p1(const int* __restrict__ dst,
                                            int* __restrict__ bcnt, int E) {
    __shared__ int h[NBUCKET];
    for (int i = threadIdx.x; i < NBUCKET; i += 256) h[i] = 0;
    __syncthreads();
    int stride = gridDim.x * 256;
    for (int i = blockIdx.x * 256 + threadIdx.x; i < E; i += stride)
        atomicAdd(&h[dst[i] >> 8], 1);
    __syncthreads();
    for (int i = threadIdx.x; i < NBUCKET; i += 256)
        if (h[i]) atomicAdd(&bcnt[i], h[i]);
}

__global__ void k_scanb(const int* __restrict__ bcnt, int* __restrict__ bbase,
                        int* __restrict__ bfill) {
    __shared__ int s[512];
    int t = threadIdx.x;
    int v = (t < NBUCKET) ? bcnt[t] : 0;
    s[t] = v; __syncthreads();
    for (int off = 1; off < 512; off <<= 1) {
        int x = (t >= off) ? s[t - off] : 0;
        __syncthreads();
        s[t] += x;
        __syncthreads();
    }
    if (t < NBUCKET) { int ex = s[t] - v; bbase[t] = ex; bfill[t] = ex; }
    if (t == NBUCKET) bbase[t] = s[511];   // = E
}

__global__ __launch_bounds__(256) void k_p2(const int* __restrict__ src,
                                            const int* __restrict__ dst,
                                            int* __restrict__ bfill,
                                            unsigned int* __restrict__ entries, int E) {
    __shared__ int h[NBUCKET];
    __shared__ int cur[NBUCKET];
    int c0 = blockIdx.x * CHUNK;
    int c1 = min(E, c0 + CHUNK);
    for (int i = threadIdx.x; i < NBUCKET; i += 256) h[i] = 0;
    __syncthreads();
    for (int i = c0 + threadIdx.x; i < c1; i += 256) atomicAdd(&h[dst[i] >> 8], 1);
    __syncthreads();
    for (int i = threadIdx.x; i < NBUCKET; i += 256)
        cur[i] = h[i] ? atomicAdd(&bfill[i], h[i]) : 0;
    __syncthreads();
    for (int i = c0 + threadIdx.x; i < c1; i += 256) {
        int d = dst[i];
        int bkt = d >> 8;
        int pos = atomicAdd(&cur[bkt], 1);
        entries[pos] = (unsigned int)src[i] | ((unsigned int)(d & 255) << 17);
    }
}

// p4x: per-bucket histogram+scan -> row_ptr, dis, col; ALSO converts x -> fp8*dis
__global__ __launch_bounds__(256) void k_p4x(const unsigned int* __restrict__ entries,
                                             const int* __restrict__ bbase,
                                             int* __restrict__ row_ptr,
                                             float* __restrict__ dis,
                                             int* __restrict__ col,
                                             const float4* __restrict__ x4,
                                             uint2* __restrict__ xb2, int N) {
    __shared__ int cnt[256];
    __shared__ int cur[256];
    __shared__ int sc[256];
    __shared__ float sdis[256];
    int b = blockIdx.x;
    int e0 = bbase[b], e1 = bbase[b + 1];
    int t = threadIdx.x;
    cnt[t] = 0; __syncthreads();
    for (int i = e0 + t; i < e1; i += 256)
        atomicAdd(&cnt[(entries[i] >> 17) & 255], 1);
    __syncthreads();
    int v = cnt[t];
    sc[t] = v; __syncthreads();
    for (int off = 1; off < 256; off <<= 1) {
        int x = (t >= off) ? sc[t - off] : 0;
        __syncthreads();
        sc[t] += x;
        __syncthreads();
    }
    int ex = sc[t] - v;
    int n = (b << 8) + t;
    float dv = rsqrtf((float)(v + 1));
    if (n <= N) row_ptr[n] = e0 + ex;
    if (n < N) dis[n] = dv;
    sdis[t] = dv;
    cur[t] = e0 + ex;
    __syncthreads();
    for (int i = e0 + t; i < e1; i += 256) {
        unsigned int en = entries[i];
        int pos = atomicAdd(&cur[(en >> 17) & 255], 1);
        col[pos] = (int)(en & 0x1FFFF);
    }
    // x -> fp8 (scaled by dis), 256 nodes x 64 dims
    for (int idx = t; idx < 256 * 8; idx += 256) {
        int node = idx >> 3, k = idx & 7;
        int gn = (b << 8) + node;
        if (gn < N) {
            float s = sdis[node];
            float4 A = x4[gn * 16 + 2 * k];
            float4 B = x4[gn * 16 + 2 * k + 1];
            uint2 u;
            u.x = pk4fp8(A.x * s, A.y * s, A.z * s, A.w * s);
            u.y = pk4fp8(B.x * s, B.y * s, B.z * s, B.w * s);
            xb2[gn * 8 + k] = u;
        }
    }
}

// ---------------- aggregation: slot-per-node, no shuffles -------------------

// D=64 fp8: 4-lane slot owns one node; lane holds 16 dims. 16 nodes per wave.
__global__ __launch_bounds__(256) void k_agg64s(
    const uint4* __restrict__ g4, const int* __restrict__ row_ptr,
    const int* __restrict__ col, const float* __restrict__ dis,
    float* __restrict__ out, int N) {
    int tid = threadIdx.x;
    int lane = tid & 63, wave = tid >> 6;
    int slot = lane >> 2, seg = lane & 3;
    int n = blockIdx.x * 64 + wave * 16 + slot;
    if (n >= N) return;
    int b = row_ptr[n], e = row_ptr[n + 1];
    float a[16];
    #pragma unroll
    for (int q = 0; q < 16; q++) a[q] = 0.f;
    acc16(g4[n * 4 + seg], a);                 // self-loop
    int i = b;
    for (; i + 4 <= e; i += 4) {
        int c0 = col[i], c1 = col[i + 1], c2 = col[i + 2], c3 = col[i + 3];
        uint4 u0 = g4[c0 * 4 + seg], u1 = g4[c1 * 4 + seg];
        uint4 u2 = g4[c2 * 4 + seg], u3 = g4[c3 * 4 + seg];
        acc16(u0, a); acc16(u1, a); acc16(u2, a); acc16(u3, a);
    }
    for (; i < e; i++) acc16(g4[col[i] * 4 + seg], a);
    float s = dis[n];
    float4* o = (float4*)(out + n * 64 + seg * 16);
    #pragma unroll
    for (int q4 = 0; q4 < 4; q4++)
        o[q4] = make_float4(s * a[q4 * 4], s * a[q4 * 4 + 1],
                            s * a[q4 * 4 + 2], s * a[q4 * 4 + 3]);
}

// D=128 fp8: 8-lane slot owns one node; lane holds 16 dims. 8 nodes per wave.
__global__ __launch_bounds__(256) void k_agg128s(
    const uint4* __restrict__ g4, const int* __restrict__ row_ptr,
    const int* __restrict__ col, const float* __restrict__ dis,
    float* __restrict__ out, int N) {
    int tid = threadIdx.x;
    int lane = tid & 63, wave = tid >> 6;
    int slot = lane >> 3, seg = lane & 7;
    int n = blockIdx.x * 32 + wave * 8 + slot;
    if (n >= N) return;
    int b = row_ptr[n], e = row_ptr[n + 1];
    float a[16];
    #pragma unroll
    for (int q = 0; q < 16; q++) a[q] = 0.f;
    acc16(g4[n * 8 + seg], a);                 // self-loop
    int i = b;
    for (; i + 4 <= e; i += 4) {
        int c0 = col[i], c1 = col[i + 1], c2 = col[i + 2], c3 = col[i + 3];
        uint4 u0 = g4[c0 * 8 + seg], u1 = g4[c1 * 8 + seg];
        uint4 u2 = g4[c2 * 8 + seg], u3 = g4[c3 * 8 + seg];
        acc16(u0, a); acc16(u1, a); acc16(u2, a); acc16(u3, a);
    }
    for (; i < e; i++) acc16(g4[col[i] * 8 + seg], a);
    float s = dis[n];
    float4* o = (float4*)(out + n * 128 + seg * 16);
    #pragma unroll
    for (int q4 = 0; q4 < 4; q4++)
        o[q4] = make_float4(s * a[q4 * 4], s * a[q4 * 4 + 1],
                            s * a[q4 * 4 + 2], s * a[q4 * 4 + 3]);
}

// L3: slot-per-node aggregate + relu(+b3) + pool. One shuffle tree per WAVE.
__global__ __launch_bounds__(256) void k_aggpools(
    const uint4* __restrict__ g4, const int* __restrict__ row_ptr,
    const int* __restrict__ col, const float* __restrict__ dis,
    const float* __restrict__ b3, float* __restrict__ partial, int N) {
    int tid = threadIdx.x;
    int lane = tid & 63, wave = tid >> 6;
    int slot = lane >> 2, seg = lane & 3;
    int n = blockIdx.x * 64 + wave * 16 + slot;
    float ap[16];
    #pragma unroll
    for (int j = 0; j < 16; j++) ap[j] = 0.f;
    if (n < N) {
        int b = row_ptr[n], e = row_ptr[n + 1];
        float a[16];
        #pragma unroll
        for (int q = 0; q < 16; q++) a[q] = 0.f;
        acc16(g4[n * 4 + seg], a);
        int i = b;
        for (; i + 4 <= e; i += 4) {
            int c0 = col[i], c1 = col[i + 1], c2 = col[i + 2], c3 = col[i + 3];
            uint4 u0 = g4[c0 * 4 + seg], u1 = g4[c1 * 4 + seg];
            uint4 u2 = g4[c2 * 4 + seg], u3 = g4[c3 * 4 + seg];
            acc16(u0, a); acc16(u1, a); acc16(u2, a); acc16(u3, a);
        }
        for (; i < e; i++) acc16(g4[col[i] * 4 + seg], a);
        float s = dis[n];
        #pragma unroll
        for (int j = 0; j < 16; j++)
            ap[j] = fmaxf(s * a[j] + b3[seg * 16 + j], 0.f);
    }
    #pragma unroll
    for (int j = 0; j < 16; j++) {
        ap[j] += __shfl_xor(ap[j], 4);
        ap[j] += __shfl_xor(ap[j], 8);
        ap[j] += __shfl_xor(ap[j], 16);
        ap[j] += __shfl_xor(ap[j], 32);
    }
    __shared__ float red[4][64];
    if (slot == 0) {
        #pragma unroll
        for (int j = 0; j < 16; j++) red[wave][seg * 16 + j] = ap[j];
    }
    __syncthreads();
    if (tid < 64)
        partial[blockIdx.x * 64 + tid] =
            red[0][tid] + red[1][tid] + red[2][tid] + red[3][tid];
}

// ---------------- dense matmuls ----------------------------------------------

// out = A[N,Din] @ W[Din,Dout]; optional (+bias, relu), (*dis); OUTM 0=f32 1=bf16 2=fp8
template <int Din, int Dout, bool BR, bool SCALE, int OUTM>
__global__ __launch_bounds__(256) void k_mm(
    const float* __restrict__ A, const float* __restrict__ W,
    const float* __restrict__ bias, const float* __restrict__ dis,
    void* __restrict__ outv, int N) {
    constexpr int CG = Dout / 4;
    constexpr int NG = 256 / CG;
    constexpr int NPT = 64 / NG;
    constexpr int STR = Din + 4;
    constexpr int K4 = Din / 4;
    __shared__ float At[64 * STR];
    const int tid = threadIdx.x;
    const int n0 = blockIdx.x * 64;
    for (int idx = tid; idx < 64 * K4; idx += 256) {
        int node = idx / K4, k4 = idx % K4;
        int gn = n0 + node;
        float4 v = (gn < N) ? ((const float4*)A)[gn * K4 + k4]
                            : make_float4(0.f, 0.f, 0.f, 0.f);
        *(float4*)&At[node * STR + 4 * k4] = v;
    }
    __syncthreads();
    const int cg = tid % CG, ng = tid / CG, nb = ng * NPT;
    float acc[NPT][4];
    #pragma unroll
    for (int t = 0; t < NPT; t++) acc[t][0] = acc[t][1] = acc[t][2] = acc[t][3] = 0.f;
    const float4* W4 = (const float4*)W;
    for (int k = 0; k < Din; k += 4) {
        float4 w0 = W4[(k + 0) * CG + cg];
        float4 w1 = W4[(k + 1) * CG + cg];
        float4 w2 = W4[(k + 2) * CG + cg];
        float4 w3 = W4[(k + 3) * CG + cg];
        #pragma unroll
        for (int t = 0; t < NPT; t++) {
            float4 a = *(const float4*)&At[(nb + t) * STR + k];
            acc[t][0] += a.x * w0.x; acc[t][1] += a.x * w0.y; acc[t][2] += a.x * w0.z; acc[t][3] += a.x * w0.w;
            acc[t][0] += a.y * w1.x; acc[t][1] += a.y * w1.y; acc[t][2] += a.y * w1.z; acc[t][3] += a.y * w1.w;
            acc[t][0] += a.z * w2.x; acc[t][1] += a.z * w2.y; acc[t][2] += a.z * w2.z; acc[t][3] += a.z * w2.w;
            acc[t][0] += a.w * w3.x; acc[t][1] += a.w * w3.y; acc[t][2] += a.w * w3.z; acc[t][3] += a.w * w3.w;
        }
    }
    float4 b4 = BR ? ((const float4*)bias)[cg] : make_float4(0.f, 0.f, 0.f, 0.f);
    #pragma unroll
    for (int t = 0; t < NPT; t++) {
        int gn = n0 + nb + t;
        if (gn < N) {
            float rx = acc[t][0] + b4.x, ry = acc[t][1] + b4.y;
            float rz = acc[t][2] + b4.z, rw = acc[t][3] + b4.w;
            if (BR) {
                rx = fmaxf(rx, 0.f); ry = fmaxf(ry, 0.f);
                rz = fmaxf(rz, 0.f); rw = fmaxf(rw, 0.f);
            }
            if (SCALE) { float s = dis[gn]; rx *= s; ry *= s; rz *= s; rw *= s; }
            if (OUTM == 0) {
                ((float4*)outv)[gn * CG + cg] = make_float4(rx, ry, rz, rw);
            } else if (OUTM == 1) {
                uint2 u; u.x = pk2b(rx, ry); u.y = pk2b(rz, rw);
                ((uint2*)outv)[gn * CG + cg] = u;
            } else {
                ((unsigned int*)outv)[gn * CG + cg] = pk4fp8(rx, ry, rz, rw);
            }
        }
    }
}

// mm3: h2s (bf16 in) @ W3 [128->64] -> g3 fp8
__global__ __launch_bounds__(256) void k_mm3b(
    const uint2* __restrict__ h2b, const float* __restrict__ W3,
    unsigned int* __restrict__ g3u, int N) {
    constexpr int STR = 132;
    __shared__ float At[64 * STR];
    const int tid = threadIdx.x;
    const int n0 = blockIdx.x * 64;
    for (int idx = tid; idx < 64 * 32; idx += 256) {
        int node = idx >> 5, k8 = idx & 31;
        int gn = n0 + node;
        uint2 u = (gn < N) ? h2b[gn * 32 + k8] : make_uint2(0u, 0u);
        *(float4*)&At[node * STR + k8 * 4] =
            make_float4(lo2f(u.x), hi2f(u.x), lo2f(u.y), hi2f(u.y));
    }
    __syncthreads();
    constexpr int CG = 16, NPT = 4;
    const int cg = tid % CG, ng = tid / CG, nb = ng * NPT;
    float acc[NPT][4];
    #pragma unroll
    for (int t = 0; t < NPT; t++) acc[t][0] = acc[t][1] = acc[t][2] = acc[t][3] = 0.f;
    const float4* W4 = (const float4*)W3;
    for (int k = 0; k < 128; k += 4) {
        float4 w0 = W4[(k + 0) * CG + cg];
        float4 w1 = W4[(k + 1) * CG + cg];
        float4 w2 = W4[(k + 2) * CG + cg];
        float4 w3 = W4[(k + 3) * CG + cg];
        #pragma unroll
        for (int t = 0; t < NPT; t++) {
            float4 a = *(const float4*)&At[(nb + t) * STR + k];
            acc[t][0] += a.x * w0.x; acc[t][1] += a.x * w0.y; acc[t][2] += a.x * w0.z; acc[t][3] += a.x * w0.w;
            acc[t][0] += a.y * w1.x; acc[t][1] += a.y * w1.y; acc[t][2] += a.y * w1.z; acc[t][3] += a.y * w1.w;
            acc[t][0] += a.z * w2.x; acc[t][1] += a.z * w2.y; acc[t][2] += a.z * w2.z; acc[t][3] += a.z * w2.w;
            acc[t][0] += a.w * w3.x; acc[t][1] += a.w * w3.y; acc[t][2] += a.w * w3.z; acc[t][3] += a.w * w3.w;
        }
    }
    #pragma unroll
    for (int t = 0; t < NPT; t++) {
        int gn = n0 + nb + t;
        if (gn < N)
            g3u[gn * 16 + cg] = pk4fp8(acc[t][0], acc[t][1], acc[t][2], acc[t][3]);
    }
}

// stage-1 partial reduction: block b reduces 16 rows of partial -> partial2[b][64]
__global__ __launch_bounds__(256) void k_red(
    const float* __restrict__ partial, float* __restrict__ partial2, int NB) {
    int blk = blockIdx.x;
    int t = threadIdx.x;
    int lane = t & 63, grp = t >> 6;
    int start = blk * 16;
    int end = min(NB, start + 16);
    float s = 0.f;
    for (int b = start + grp; b < end; b += 4) s += partial[b * 64 + lane];
    __shared__ float red[256];
    red[t] = s; __syncthreads();
    if (t < 64)
        partial2[blk * 64 + t] = red[t] + red[t + 64] + red[t + 128] + red[t + 192];
}

// reduce partial2 -> mean pool -> fc(relu) -> fc -> softmax -> out[2]
__global__ __launch_bounds__(256) void k_head(
    const float* __restrict__ partial, const float* __restrict__ Wc1,
    const float* __restrict__ bc1, const float* __restrict__ Wc2,
    const float* __restrict__ bc2, float* __restrict__ out, int NB, float invN) {
    __shared__ float red[256];
    __shared__ float pooled[64];
    __shared__ float z[32];
    __shared__ float lg[2];
    int t = threadIdx.x;
    int lane = t & 63, grp = t >> 6;
    float s = 0.f;
    for (int b = grp; b < NB; b += 4) s += partial[b * 64 + lane];
    red[t] = s; __syncthreads();
    if (t < 64) pooled[t] = (red[t] + red[t + 64] + red[t + 128] + red[t + 192]) * invN;
    __syncthreads();
    if (t < 32) {
        float a = bc1[t];
        for (int l = 0; l < 64; l++) a += pooled[l] * Wc1[l * 32 + t];
        z[t] = fmaxf(a, 0.f);
    }
    __syncthreads();
    if (t < 2) {
        float a = bc2[t];
        for (int j = 0; j < 32; j++) a += z[j] * Wc2[j * 2 + t];
        lg[t] = a;
    }
    __syncthreads();
    if (t == 0) {
        float m = fmaxf(lg[0], lg[1]);
        float e0 = __expf(lg[0] - m), e1 = __expf(lg[1] - m);
        float inv = 1.f / (e0 + e1);
        out[0] = e0 * inv;
        out[1] = e1 * inv;
    }
}

// ---------------- launch ----------------

extern "C" void kernel_launch(void* const* d_in, const int* in_sizes, int n_in,
                              void* d_out, int out_size, void* d_ws, size_t ws_size,
                              hipStream_t stream) {
    (void)in_sizes; (void)n_in; (void)out_size; (void)ws_size;
    const int N = NN, E = NE;

    const float* x   = (const float*)d_in[0];
    const int*   ei  = (const int*)d_in[1];
    const int*   srcp = ei;
    const int*   dstp = ei + E;
    const float* W1 = (const float*)d_in[2];
    const float* b1 = (const float*)d_in[3];
    const float* W2 = (const float*)d_in[4];
    const float* b2 = (const float*)d_in[5];
    const float* W3 = (const float*)d_in[6];
    const float* b3 = (const float*)d_in[7];
    const float* Wc1 = (const float*)d_in[8];
    const float* bc1 = (const float*)d_in[9];
    const float* Wc2 = (const float*)d_in[10];
    const float* bc2 = (const float*)d_in[11];
    float* out = (float*)d_out;

    char* base = (char*)d_ws;
    size_t off = 0;
    auto carve = [&](size_t bytes) -> char* {
        char* p = base + off;
        off = (off + bytes + 255) & ~(size_t)255;
        return p;
    };
    int*   bcnt    = (int*)carve((size_t)NBUCKET * 4);
    int*   bbase   = (int*)carve((size_t)(NBUCKET + 1) * 4);
    int*   bfill   = (int*)carve((size_t)NBUCKET * 4);
    int*   row_ptr = (int*)carve((size_t)(N + 1) * 4);
    int*   col     = (int*)carve((size_t)E * 4);
    float* dis     = (float*)carve((size_t)N * 4);
    float* partial = (float*)carve((size_t)1600 * 64 * 4);
    float* partial2= (float*)carve((size_t)128 * 64 * 4);
    unsigned int* entries = (unsigned int*)carve((size_t)E * 4);
    unsigned int* xb      = (unsigned int*)carve((size_t)N * 64);   // fp8 [N,64]
    unsigned int* h1u     = (unsigned int*)carve((size_t)N * 128);  // fp8 [N,128]
    uint2*        h2b     = (uint2*)carve((size_t)N * 128 * 2);     // bf16 [N,128]
    unsigned int* g3u     = (unsigned int*)carve((size_t)N * 64);   // fp8 [N,64]
    float*        bufA    = (float*)carve((size_t)N * 128 * 4);     // fp32 agg out

    // ---- CSR build + x->fp8 ----
    k_zero32<<<(NBUCKET + 255) / 256, 256, 0, stream>>>(bcnt, NBUCKET);
    k_p1<<<512, 256, 0, stream>>>(dstp, bcnt, E);
    k_scanb<<<1, 512, 0, stream>>>(bcnt, bbase, bfill);
    k_p2<<<(E + CHUNK - 1) / CHUNK, 256, 0, stream>>>(srcp, dstp, bfill, entries, E);
    k_p4x<<<NBUCKET, 256, 0, stream>>>(entries, bbase, row_ptr, dis, col,
                                       (const float4*)x, (uint2*)xb, N);

    const int NB64 = (N + 63) / 64;    // 1563 — slot-per-node D=64 & mm grids
    const int NB32 = (N + 31) / 32;    // 3125 — slot-per-node D=128 grid

    // ---- layer 1: aggregate xb (fp8) -> fp32, mm 64->128 -> h1 fp8 ----
    k_agg64s<<<NB64, 256, 0, stream>>>((const uint4*)xb, row_ptr, col, dis, bufA, N);
    k_mm<64, 128, true, true, 2><<<NB64, 256, 0, stream>>>(bufA, W1, b1, dis, h1u, N);

    // ---- layer 2: aggregate h1 (fp8) -> fp32, mm 128->128 -> h2s bf16 ----
    k_agg128s<<<NB32, 256, 0, stream>>>((const uint4*)h1u, row_ptr, col, dis, bufA, N);
    k_mm<128, 128, true, true, 1><<<NB64, 256, 0, stream>>>(bufA, W2, b2, dis, h2b, N);

    // ---- layer 3: mm 128->64 -> g3 fp8, then aggregate+relu+pool (fused) ----
    k_mm3b<<<NB64, 256, 0, stream>>>(h2b, W3, g3u, N);
    k_aggpools<<<NB64, 256, 0, stream>>>((const uint4*)g3u, row_ptr, col, dis, b3, partial, N);

    // ---- two-stage pooled reduction + head ----
    const int NRED = (NB64 + 15) / 16;   // 98
    k_red<<<NRED, 256, 0, stream>>>(partial, partial2, NB64);
    k_head<<<1, 256, 0, stream>>>(partial2, Wc1, bc1, Wc2, bc2, out, NRED, 1.0f / (float)N);
}

// Round 8
// 303.902 us; speedup vs baseline: 1.8913x; 1.2889x over previous
//
#include <hip/hip_runtime.h>

// Problem constants (from reference)
#define NN 100000
#define NE 1600000
#define NBUCKET 391   // ceil(NN / 256)
#define CHUNK 4096    // edges per block in p2 scatter

typedef __attribute__((ext_vector_type(2))) float v2f;
typedef __attribute__((ext_vector_type(8))) short bf16x8;   // 8 bf16 = 4 VGPRs
typedef __attribute__((ext_vector_type(4))) float f32x4;

// ---------------- fp8 (OCP e4m3) helpers — storage only, math in fp32 ------

__device__ __forceinline__ unsigned int pk4fp8(float a, float b, float c, float d) {
    int t = __builtin_amdgcn_cvt_pk_fp8_f32(a, b, 0, false);   // bytes 0,1
    t = __builtin_amdgcn_cvt_pk_fp8_f32(c, d, t, true);        // bytes 2,3
    return (unsigned int)t;
}
__device__ __forceinline__ void acc4(unsigned int u, float* a) {
    v2f p0 = __builtin_amdgcn_cvt_pk_f32_fp8((int)u, false);
    v2f p1 = __builtin_amdgcn_cvt_pk_f32_fp8((int)u, true);
    a[0] += p0.x; a[1] += p0.y; a[2] += p1.x; a[3] += p1.y;
}
__device__ __forceinline__ void acc16(uint4 u, float* a) {
    acc4(u.x, a); acc4(u.y, a + 4); acc4(u.z, a + 8); acc4(u.w, a + 12);
}

// ---------------- bf16 helpers ----------------------------------------------

__device__ __forceinline__ unsigned short f2b(float f) {
    unsigned int u; __builtin_memcpy(&u, &f, 4);
    unsigned int r = (u + 0x7fffu + ((u >> 16) & 1u)) >> 16;  // RNE
    return (unsigned short)r;
}
__device__ __forceinline__ unsigned int pk2b(float a, float b) {
    return (unsigned int)f2b(a) | ((unsigned int)f2b(b) << 16);
}

// ---------------- CSR build via bucketed counting sort ----------------------

__global__ void k_zero32(int* __restrict__ p, int n) {
    int i = blockIdx.x * 256 + threadIdx.x;
    if (i < n) p[i] = 0;
}

__global__ __launch_bounds__(256) void k_p1(const int* __restrict__ dst,
                                            int* __restrict__ bcnt, int E) {
    __shared__ int h[NBUCKET];
    for (int i = threadIdx.x; i < NBUCKET; i += 256) h[i] = 0;
    __syncthreads();
    int stride = gridDim.x * 256;
    for (int i = blockIdx.x * 256 + threadIdx.x; i < E; i += stride)
        atomicAdd(&h[dst[i] >> 8], 1);
    __syncthreads();
    for (int i = threadIdx.x; i < NBUCKET; i += 256)
        if (h[i]) atomicAdd(&bcnt[i], h[i]);
}

__global__ void k_scanb(const int* __restrict__ bcnt, int* __restrict__ bbase,
                        int* __restrict__ bfill) {
    __shared__ int s[512];
    int t = threadIdx.x;
    int v = (t < NBUCKET) ? bcnt[t] : 0;
    s[t] = v; __syncthreads();
    for (int off = 1; off < 512; off <<= 1) {
        int x = (t >= off) ? s[t - off] : 0;
        __syncthreads();
        s[t] += x;
        __syncthreads();
    }
    if (t < NBUCKET) { int ex = s[t] - v; bbase[t] = ex; bfill[t] = ex; }
    if (t == NBUCKET) bbase[t] = s[511];   // = E
}

__global__ __launch_bounds__(256) void k_p2(const int* __restrict__ src,
                                            const int* __restrict__ dst,
                                            int* __restrict__ bfill,
                                            unsigned int* __restrict__ entries, int E) {
    __shared__ int h[NBUCKET];
    __shared__ int cur[NBUCKET];
    int c0 = blockIdx.x * CHUNK;
    int c1 = min(E, c0 + CHUNK);
    for (int i = threadIdx.x; i < NBUCKET; i += 256) h[i] = 0;
    __syncthreads();
    for (int i = c0 + threadIdx.x; i < c1; i += 256) atomicAdd(&h[dst[i] >> 8], 1);
    __syncthreads();
    for (int i = threadIdx.x; i < NBUCKET; i += 256)
        cur[i] = h[i] ? atomicAdd(&bfill[i], h[i]) : 0;
    __syncthreads();
    for (int i = c0 + threadIdx.x; i < c1; i += 256) {
        int d = dst[i];
        int bkt = d >> 8;
        int pos = atomicAdd(&cur[bkt], 1);
        entries[pos] = (unsigned int)src[i] | ((unsigned int)(d & 255) << 17);
    }
}

// p4x: per-bucket histogram+scan -> row_ptr, dis, col; ALSO converts x -> fp8*dis
__global__ __launch_bounds__(256) void k_p4x(const unsigned int* __restrict__ entries,
                                             const int* __restrict__ bbase,
                                             int* __restrict__ row_ptr,
                                             float* __restrict__ dis,
                                             int* __restrict__ col,
                                             const float4* __restrict__ x4,
                                             uint2* __restrict__ xb2, int N) {
    __shared__ int cnt[256];
    __shared__ int cur[256];
    __shared__ int sc[256];
    __shared__ float sdis[256];
    int b = blockIdx.x;
    int e0 = bbase[b], e1 = bbase[b + 1];
    int t = threadIdx.x;
    cnt[t] = 0; __syncthreads();
    for (int i = e0 + t; i < e1; i += 256)
        atomicAdd(&cnt[(entries[i] >> 17) & 255], 1);
    __syncthreads();
    int v = cnt[t];
    sc[t] = v; __syncthreads();
    for (int off = 1; off < 256; off <<= 1) {
        int x = (t >= off) ? sc[t - off] : 0;
        __syncthreads();
        sc[t] += x;
        __syncthreads();
    }
    int ex = sc[t] - v;
    int n = (b << 8) + t;
    float dv = rsqrtf((float)(v + 1));
    if (n <= N) row_ptr[n] = e0 + ex;
    if (n < N) dis[n] = dv;
    sdis[t] = dv;
    cur[t] = e0 + ex;
    __syncthreads();
    for (int i = e0 + t; i < e1; i += 256) {
        unsigned int en = entries[i];
        int pos = atomicAdd(&cur[(en >> 17) & 255], 1);
        col[pos] = (int)(en & 0x1FFFF);
    }
    // x -> fp8 (scaled by dis), 256 nodes x 64 dims
    for (int idx = t; idx < 256 * 8; idx += 256) {
        int node = idx >> 3, k = idx & 7;
        int gn = (b << 8) + node;
        if (gn < N) {
            float s = sdis[node];
            float4 A = x4[gn * 16 + 2 * k];
            float4 B = x4[gn * 16 + 2 * k + 1];
            uint2 u;
            u.x = pk4fp8(A.x * s, A.y * s, A.z * s, A.w * s);
            u.y = pk4fp8(B.x * s, B.y * s, B.z * s, B.w * s);
            xb2[gn * 8 + k] = u;
        }
    }
}

// ---------------- weight pre-swizzle (fp32 -> bf16 MFMA A-fragment layout) --
// Wp entry e (uint4 = 8 bf16, j=0..7) for a given W[Din][Dout]:
//   e = (kt*4+q)*Dout + ch ; source W[kt*32+q*8+j][ch]
// Offsets in uint4 units: W1 @ 0 (1024), W2 @ 1024 (2048), W3 @ 3072 (1024).
__global__ __launch_bounds__(256) void k_wcvt(
    const float* __restrict__ W1, const float* __restrict__ W2,
    const float* __restrict__ W3, uint4* __restrict__ Wp) {
    int t = blockIdx.x * 256 + threadIdx.x;   // 0..4095
    const float* W; int Dout, e, base;
    if (t < 1024)       { W = W1; Dout = 128; e = t;        base = 0; }
    else if (t < 3072)  { W = W2; Dout = 128; e = t - 1024; base = 1024; }
    else                { W = W3; Dout = 64;  e = t - 3072; base = 3072; }
    int k4q = e / Dout, ch = e % Dout;
    int k0 = (k4q >> 2) * 32 + (k4q & 3) * 8;
    float v[8];
    #pragma unroll
    for (int j = 0; j < 8; j++) v[j] = W[(k0 + j) * Dout + ch];
    uint4 u;
    u.x = pk2b(v[0], v[1]); u.y = pk2b(v[2], v[3]);
    u.z = pk2b(v[4], v[5]); u.w = pk2b(v[6], v[7]);
    Wp[base + e] = u;
}

// ---------------- aggregation: slot-per-node, fp8 gather -> bf16 out --------

// D=64 fp8: 4-lane slot owns one node; lane holds 16 dims. bf16 out [N,64].
__global__ __launch_bounds__(256) void k_agg64s(
    const uint4* __restrict__ g4, const int* __restrict__ row_ptr,
    const int* __restrict__ col, const float* __restrict__ dis,
    uint4* __restrict__ outb, int N) {
    int tid = threadIdx.x;
    int lane = tid & 63, wave = tid >> 6;
    int slot = lane >> 2, seg = lane & 3;
    int n = blockIdx.x * 64 + wave * 16 + slot;
    if (n >= N) return;
    int b = row_ptr[n], e = row_ptr[n + 1];
    float a[16];
    #pragma unroll
    for (int q = 0; q < 16; q++) a[q] = 0.f;
    acc16(g4[n * 4 + seg], a);                 // self-loop
    int i = b;
    for (; i + 4 <= e; i += 4) {
        int c0 = col[i], c1 = col[i + 1], c2 = col[i + 2], c3 = col[i + 3];
        uint4 u0 = g4[c0 * 4 + seg], u1 = g4[c1 * 4 + seg];
        uint4 u2 = g4[c2 * 4 + seg], u3 = g4[c3 * 4 + seg];
        acc16(u0, a); acc16(u1, a); acc16(u2, a); acc16(u3, a);
    }
    for (; i < e; i++) acc16(g4[col[i] * 4 + seg], a);
    float s = dis[n];
    uint4 u0, u1;
    u0.x = pk2b(s*a[0],  s*a[1]);  u0.y = pk2b(s*a[2],  s*a[3]);
    u0.z = pk2b(s*a[4],  s*a[5]);  u0.w = pk2b(s*a[6],  s*a[7]);
    u1.x = pk2b(s*a[8],  s*a[9]);  u1.y = pk2b(s*a[10], s*a[11]);
    u1.z = pk2b(s*a[12], s*a[13]); u1.w = pk2b(s*a[14], s*a[15]);
    outb[n * 8 + seg * 2]     = u0;            // row = 64 bf16 = 8 uint4
    outb[n * 8 + seg * 2 + 1] = u1;
}

// D=128 fp8: 8-lane slot owns one node; lane holds 16 dims. bf16 out [N,128].
__global__ __launch_bounds__(256) void k_agg128s(
    const uint4* __restrict__ g4, const int* __restrict__ row_ptr,
    const int* __restrict__ col, const float* __restrict__ dis,
    uint4* __restrict__ outb, int N) {
    int tid = threadIdx.x;
    int lane = tid & 63, wave = tid >> 6;
    int slot = lane >> 3, seg = lane & 7;
    int n = blockIdx.x * 32 + wave * 8 + slot;
    if (n >= N) return;
    int b = row_ptr[n], e = row_ptr[n + 1];
    float a[16];
    #pragma unroll
    for (int q = 0; q < 16; q++) a[q] = 0.f;
    acc16(g4[n * 8 + seg], a);                 // self-loop
    int i = b;
    for (; i + 4 <= e; i += 4) {
        int c0 = col[i], c1 = col[i + 1], c2 = col[i + 2], c3 = col[i + 3];
        uint4 u0 = g4[c0 * 8 + seg], u1 = g4[c1 * 8 + seg];
        uint4 u2 = g4[c2 * 8 + seg], u3 = g4[c3 * 8 + seg];
        acc16(u0, a); acc16(u1, a); acc16(u2, a); acc16(u3, a);
    }
    for (; i < e; i++) acc16(g4[col[i] * 8 + seg], a);
    float s = dis[n];
    uint4 u0, u1;
    u0.x = pk2b(s*a[0],  s*a[1]);  u0.y = pk2b(s*a[2],  s*a[3]);
    u0.z = pk2b(s*a[4],  s*a[5]);  u0.w = pk2b(s*a[6],  s*a[7]);
    u1.x = pk2b(s*a[8],  s*a[9]);  u1.y = pk2b(s*a[10], s*a[11]);
    u1.z = pk2b(s*a[12], s*a[13]); u1.w = pk2b(s*a[14], s*a[15]);
    outb[n * 16 + seg * 2]     = u0;           // row = 128 bf16 = 16 uint4
    outb[n * 16 + seg * 2 + 1] = u1;
}

// L3: slot-per-node aggregate (fp8) + relu(+b3) + pool. One shuffle tree/wave.
__global__ __launch_bounds__(256) void k_aggpools(
    const uint4* __restrict__ g4, const int* __restrict__ row_ptr,
    const int* __restrict__ col, const float* __restrict__ dis,
    const float* __restrict__ b3, float* __restrict__ partial, int N) {
    int tid = threadIdx.x;
    int lane = tid & 63, wave = tid >> 6;
    int slot = lane >> 2, seg = lane & 3;
    int n = blockIdx.x * 64 + wave * 16 + slot;
    float ap[16];
    #pragma unroll
    for (int j = 0; j < 16; j++) ap[j] = 0.f;
    if (n < N) {
        int b = row_ptr[n], e = row_ptr[n + 1];
        float a[16];
        #pragma unroll
        for (int q = 0; q < 16; q++) a[q] = 0.f;
        acc16(g4[n * 4 + seg], a);
        int i = b;
        for (; i + 4 <= e; i += 4) {
            int c0 = col[i], c1 = col[i + 1], c2 = col[i + 2], c3 = col[i + 3];
            uint4 u0 = g4[c0 * 4 + seg], u1 = g4[c1 * 4 + seg];
            uint4 u2 = g4[c2 * 4 + seg], u3 = g4[c3 * 4 + seg];
            acc16(u0, a); acc16(u1, a); acc16(u2, a); acc16(u3, a);
        }
        for (; i < e; i++) acc16(g4[col[i] * 4 + seg], a);
        float s = dis[n];
        #pragma unroll
        for (int j = 0; j < 16; j++)
            ap[j] = fmaxf(s * a[j] + b3[seg * 16 + j], 0.f);
    }
    #pragma unroll
    for (int j = 0; j < 16; j++) {
        ap[j] += __shfl_xor(ap[j], 4);
        ap[j] += __shfl_xor(ap[j], 8);
        ap[j] += __shfl_xor(ap[j], 16);
        ap[j] += __shfl_xor(ap[j], 32);
    }
    __shared__ float red[4][64];
    if (slot == 0) {
        #pragma unroll
        for (int j = 0; j < 16; j++) red[wave][seg * 16 + j] = ap[j];
    }
    __syncthreads();
    if (tid < 64)
        partial[blockIdx.x * 64 + tid] =
            red[0][tid] + red[1][tid] + red[2][tid] + red[3][tid];
}

// ---------------- MFMA matmuls (no LDS, no barriers) ------------------------
// D = W^T · X^T per 16x16 tile:  A-frag = W (ch=lane&15, k=quad*8+j),
// B-frag = X row (node=lane&15, k=quad*8+j), C/D: col=node, row=ch(quad*4+reg).
// OUTM: 1 = bf16 out + bias+relu+dis ; 2 = fp8 out + bias+relu+dis ; 3 = fp8 plain
template <int Din, int Dout, int OUTM>
__global__ __launch_bounds__(256) void k_mmx(
    const uint4* __restrict__ Xb,     // bf16 [N][Din], Din/8 uint4 per row
    const uint4* __restrict__ Wp,     // packed bf16 fragments
    const float* __restrict__ bias, const float* __restrict__ dis,
    void* __restrict__ outv, int N) {
    constexpr int KT = Din / 32;
    constexpr int CT = Dout / 16;
    const int tid = threadIdx.x, wave = tid >> 6, lane = tid & 63;
    const int quad = lane >> 4, l16 = lane & 15;
    const int node = blockIdx.x * 64 + wave * 16 + l16;
    const bool valid = node < N;
    const int nc = valid ? node : (N - 1);
    // B fragments: this node's X row, one uint4 (8 bf16) per k-tile
    bf16x8 bfrag[KT];
    const uint4* xrow = Xb + (size_t)nc * (Din / 8);
    #pragma unroll
    for (int kt = 0; kt < KT; kt++) {
        uint4 u = xrow[kt * 4 + quad];
        bfrag[kt] = *(bf16x8*)&u;
    }
    const float s = (OUTM != 3 && valid) ? dis[node] : 0.f;
    #pragma unroll
    for (int ct = 0; ct < CT; ct++) {
        f32x4 c = {0.f, 0.f, 0.f, 0.f};
        #pragma unroll
        for (int kt = 0; kt < KT; kt++) {
            uint4 wu = Wp[(kt * 4 + quad) * Dout + ct * 16 + l16];
            bf16x8 afrag = *(bf16x8*)&wu;
            c = __builtin_amdgcn_mfma_f32_16x16x32_bf16(afrag, bfrag[kt], c, 0, 0, 0);
        }
        if (valid) {
            const int chb = ct * 16 + quad * 4;
            float r0 = c[0], r1 = c[1], r2 = c[2], r3 = c[3];
            if (OUTM != 3) {
                r0 = fmaxf(r0 + bias[chb + 0], 0.f) * s;
                r1 = fmaxf(r1 + bias[chb + 1], 0.f) * s;
                r2 = fmaxf(r2 + bias[chb + 2], 0.f) * s;
                r3 = fmaxf(r3 + bias[chb + 3], 0.f) * s;
            }
            if (OUTM == 1) {
                uint2 u; u.x = pk2b(r0, r1); u.y = pk2b(r2, r3);
                ((uint2*)outv)[(size_t)node * (Dout / 4) + ct * 4 + quad] = u;
            } else {
                ((unsigned int*)outv)[(size_t)node * (Dout / 4) + ct * 4 + quad] =
                    pk4fp8(r0, r1, r2, r3);
            }
        }
    }
}

// stage-1 partial reduction: block b reduces 16 rows of partial -> partial2[b][64]
__global__ __launch_bounds__(256) void k_red(
    const float* __restrict__ partial, float* __restrict__ partial2, int NB) {
    int blk = blockIdx.x;
    int t = threadIdx.x;
    int lane = t & 63, grp = t >> 6;
    int start = blk * 16;
    int end = min(NB, start + 16);
    float s = 0.f;
    for (int b = start + grp; b < end; b += 4) s += partial[b * 64 + lane];
    __shared__ float red[256];
    red[t] = s; __syncthreads();
    if (t < 64)
        partial2[blk * 64 + t] = red[t] + red[t + 64] + red[t + 128] + red[t + 192];
}

// reduce partial2 -> mean pool -> fc(relu) -> fc -> softmax -> out[2]
__global__ __launch_bounds__(256) void k_head(
    const float* __restrict__ partial, const float* __restrict__ Wc1,
    const float* __restrict__ bc1, const float* __restrict__ Wc2,
    const float* __restrict__ bc2, float* __restrict__ out, int NB, float invN) {
    __shared__ float red[256];
    __shared__ float pooled[64];
    __shared__ float z[32];
    __shared__ float lg[2];
    int t = threadIdx.x;
    int lane = t & 63, grp = t >> 6;
    float s = 0.f;
    for (int b = grp; b < NB; b += 4) s += partial[b * 64 + lane];
    red[t] = s; __syncthreads();
    if (t < 64) pooled[t] = (red[t] + red[t + 64] + red[t + 128] + red[t + 192]) * invN;
    __syncthreads();
    if (t < 32) {
        float a = bc1[t];
        for (int l = 0; l < 64; l++) a += pooled[l] * Wc1[l * 32 + t];
        z[t] = fmaxf(a, 0.f);
    }
    __syncthreads();
    if (t < 2) {
        float a = bc2[t];
        for (int j = 0; j < 32; j++) a += z[j] * Wc2[j * 2 + t];
        lg[t] = a;
    }
    __syncthreads();
    if (t == 0) {
        float m = fmaxf(lg[0], lg[1]);
        float e0 = __expf(lg[0] - m), e1 = __expf(lg[1] - m);
        float inv = 1.f / (e0 + e1);
        out[0] = e0 * inv;
        out[1] = e1 * inv;
    }
}

// ---------------- launch ----------------

extern "C" void kernel_launch(void* const* d_in, const int* in_sizes, int n_in,
                              void* d_out, int out_size, void* d_ws, size_t ws_size,
                              hipStream_t stream) {
    (void)in_sizes; (void)n_in; (void)out_size; (void)ws_size;
    const int N = NN, E = NE;

    const float* x   = (const float*)d_in[0];
    const int*   ei  = (const int*)d_in[1];
    const int*   srcp = ei;
    const int*   dstp = ei + E;
    const float* W1 = (const float*)d_in[2];
    const float* b1 = (const float*)d_in[3];
    const float* W2 = (const float*)d_in[4];
    const float* b2 = (const float*)d_in[5];
    const float* W3 = (const float*)d_in[6];
    const float* b3 = (const float*)d_in[7];
    const float* Wc1 = (const float*)d_in[8];
    const float* bc1 = (const float*)d_in[9];
    const float* Wc2 = (const float*)d_in[10];
    const float* bc2 = (const float*)d_in[11];
    float* out = (float*)d_out;

    char* base = (char*)d_ws;
    size_t off = 0;
    auto carve = [&](size_t bytes) -> char* {
        char* p = base + off;
        off = (off + bytes + 255) & ~(size_t)255;
        return p;
    };
    int*   bcnt    = (int*)carve((size_t)NBUCKET * 4);
    int*   bbase   = (int*)carve((size_t)(NBUCKET + 1) * 4);
    int*   bfill   = (int*)carve((size_t)NBUCKET * 4);
    int*   row_ptr = (int*)carve((size_t)(N + 1) * 4);
    int*   col     = (int*)carve((size_t)E * 4);
    float* dis     = (float*)carve((size_t)N * 4);
    float* partial = (float*)carve((size_t)1600 * 64 * 4);
    float* partial2= (float*)carve((size_t)128 * 64 * 4);
    uint4* Wp      = (uint4*)carve((size_t)4096 * 16);              // packed bf16 weights
    unsigned int* entries = (unsigned int*)carve((size_t)E * 4);
    unsigned int* xb      = (unsigned int*)carve((size_t)N * 64);   // fp8 [N,64]
    unsigned int* h1u     = (unsigned int*)carve((size_t)N * 128);  // fp8 [N,128]
    uint4*        h2b     = (uint4*)carve((size_t)N * 128 * 2);     // bf16 [N,128]
    unsigned int* g3u     = (unsigned int*)carve((size_t)N * 64);   // fp8 [N,64]
    uint4*        bufB    = (uint4*)carve((size_t)N * 128 * 2);     // bf16 agg out

    // ---- CSR build + x->fp8 + weight pre-swizzle ----
    k_zero32<<<(NBUCKET + 255) / 256, 256, 0, stream>>>(bcnt, NBUCKET);
    k_p1<<<512, 256, 0, stream>>>(dstp, bcnt, E);
    k_scanb<<<1, 512, 0, stream>>>(bcnt, bbase, bfill);
    k_p2<<<(E + CHUNK - 1) / CHUNK, 256, 0, stream>>>(srcp, dstp, bfill, entries, E);
    k_wcvt<<<16, 256, 0, stream>>>(W1, W2, W3, Wp);
    k_p4x<<<NBUCKET, 256, 0, stream>>>(entries, bbase, row_ptr, dis, col,
                                       (const float4*)x, (uint2*)xb, N);

    const int NB64 = (N + 63) / 64;    // 1563
    const int NB32 = (N + 31) / 32;    // 3125

    // ---- layer 1: aggregate xb (fp8) -> bf16, MFMA 64->128 -> h1 fp8 ----
    k_agg64s<<<NB64, 256, 0, stream>>>((const uint4*)xb, row_ptr, col, dis, bufB, N);
    k_mmx<64, 128, 2><<<NB64, 256, 0, stream>>>(bufB, Wp, b1, dis, h1u, N);

    // ---- layer 2: aggregate h1 (fp8) -> bf16, MFMA 128->128 -> h2 bf16 ----
    k_agg128s<<<NB32, 256, 0, stream>>>((const uint4*)h1u, row_ptr, col, dis, bufB, N);
    k_mmx<128, 128, 1><<<NB64, 256, 0, stream>>>(bufB, Wp + 1024, b2, dis, h2b, N);

    // ---- layer 3: MFMA 128->64 -> g3 fp8, then aggregate+relu+pool ----
    k_mmx<128, 64, 3><<<NB64, 256, 0, stream>>>(h2b, Wp + 3072, nullptr, nullptr, g3u, N);
    k_aggpools<<<NB64, 256, 0, stream>>>((const uint4*)g3u, row_ptr, col, dis, b3, partial, N);

    // ---- two-stage pooled reduction + head ----
    const int NRED = (NB64 + 15) / 16;   // 98
    k_red<<<NRED, 256, 0, stream>>>(partial, partial2, NB64);
    k_head<<<1, 256, 0, stream>>>(partial2, Wc1, bc1, Wc2, bc2, out, NRED, 1.0f / (float)N);
}

// Round 9
// 281.922 us; speedup vs baseline: 2.0388x; 1.0780x over previous
//
#include <hip/hip_runtime.h>

// Problem constants (from reference)
#define NN 100000
#define NE 1600000
#define NBUCKET 391   // ceil(NN / 256)
#define CHUNK 4096    // edges per block in p2 scatter

typedef __attribute__((ext_vector_type(2))) float v2f;
typedef __attribute__((ext_vector_type(8))) short bf16x8;   // 8 bf16 = 4 VGPRs
typedef __attribute__((ext_vector_type(4))) float f32x4;

// ---------------- fp8 (OCP e4m3) helpers — storage only, math in fp32 ------

__device__ __forceinline__ unsigned int pk4fp8(float a, float b, float c, float d) {
    int t = __builtin_amdgcn_cvt_pk_fp8_f32(a, b, 0, false);   // bytes 0,1
    t = __builtin_amdgcn_cvt_pk_fp8_f32(c, d, t, true);        // bytes 2,3
    return (unsigned int)t;
}
__device__ __forceinline__ void acc4(unsigned int u, float* a) {
    v2f p0 = __builtin_amdgcn_cvt_pk_f32_fp8((int)u, false);
    v2f p1 = __builtin_amdgcn_cvt_pk_f32_fp8((int)u, true);
    a[0] += p0.x; a[1] += p0.y; a[2] += p1.x; a[3] += p1.y;
}
__device__ __forceinline__ void acc16(uint4 u, float* a) {
    acc4(u.x, a); acc4(u.y, a + 4); acc4(u.z, a + 8); acc4(u.w, a + 12);
}

// ---------------- bf16 helpers ----------------------------------------------

__device__ __forceinline__ unsigned short f2b(float f) {
    unsigned int u; __builtin_memcpy(&u, &f, 4);
    unsigned int r = (u + 0x7fffu + ((u >> 16) & 1u)) >> 16;  // RNE
    return (unsigned short)r;
}
__device__ __forceinline__ unsigned int pk2b(float a, float b) {
    return (unsigned int)f2b(a) | ((unsigned int)f2b(b) << 16);
}

// ---------------- init: zero bcnt + weight pre-swizzle ----------------------
// Wp entry e (uint4 = 8 bf16, j=0..7) for W[Din][Dout]:
//   e = (kt*4+q)*Dout + ch ; source W[kt*32+q*8+j][ch]
// Offsets (uint4): W1 @ 0 (1024), W2 @ 1024 (2048), W3 @ 3072 (1024).
__global__ __launch_bounds__(256) void k_init(
    const float* __restrict__ W1, const float* __restrict__ W2,
    const float* __restrict__ W3, uint4* __restrict__ Wp,
    int* __restrict__ bcnt) {
    int t = blockIdx.x * 256 + threadIdx.x;
    if (t < 4096) {
        const float* W; int Dout, e, base;
        if (t < 1024)       { W = W1; Dout = 128; e = t;        base = 0; }
        else if (t < 3072)  { W = W2; Dout = 128; e = t - 1024; base = 1024; }
        else                { W = W3; Dout = 64;  e = t - 3072; base = 3072; }
        int k4q = e / Dout, ch = e % Dout;
        int k0 = (k4q >> 2) * 32 + (k4q & 3) * 8;
        float v[8];
        #pragma unroll
        for (int j = 0; j < 8; j++) v[j] = W[(k0 + j) * Dout + ch];
        uint4 u;
        u.x = pk2b(v[0], v[1]); u.y = pk2b(v[2], v[3]);
        u.z = pk2b(v[4], v[5]); u.w = pk2b(v[6], v[7]);
        Wp[base + e] = u;
    } else {
        int i = t - 4096;
        if (i < NBUCKET) bcnt[i] = 0;
    }
}

// ---------------- CSR build via bucketed counting sort ----------------------

__global__ __launch_bounds__(256) void k_p1(const int* __restrict__ dst,
                                            int* __restrict__ bcnt, int E) {
    __shared__ int h[NBUCKET];
    for (int i = threadIdx.x; i < NBUCKET; i += 256) h[i] = 0;
    __syncthreads();
    int stride = gridDim.x * 256;
    for (int i = blockIdx.x * 256 + threadIdx.x; i < E; i += stride)
        atomicAdd(&h[dst[i] >> 8], 1);
    __syncthreads();
    for (int i = threadIdx.x; i < NBUCKET; i += 256)
        if (h[i]) atomicAdd(&bcnt[i], h[i]);
}

__global__ void k_scanb(const int* __restrict__ bcnt, int* __restrict__ bbase,
                        int* __restrict__ bfill) {
    __shared__ int s[512];
    int t = threadIdx.x;
    int v = (t < NBUCKET) ? bcnt[t] : 0;
    s[t] = v; __syncthreads();
    for (int off = 1; off < 512; off <<= 1) {
        int x = (t >= off) ? s[t - off] : 0;
        __syncthreads();
        s[t] += x;
        __syncthreads();
    }
    if (t < NBUCKET) { int ex = s[t] - v; bbase[t] = ex; bfill[t] = ex; }
    if (t == NBUCKET) bbase[t] = s[511];   // = E
}

__global__ __launch_bounds__(256) void k_p2(const int* __restrict__ src,
                                            const int* __restrict__ dst,
                                            int* __restrict__ bfill,
                                            unsigned int* __restrict__ entries, int E) {
    __shared__ int h[NBUCKET];
    __shared__ int cur[NBUCKET];
    int c0 = blockIdx.x * CHUNK;
    int c1 = min(E, c0 + CHUNK);
    for (int i = threadIdx.x; i < NBUCKET; i += 256) h[i] = 0;
    __syncthreads();
    for (int i = c0 + threadIdx.x; i < c1; i += 256) atomicAdd(&h[dst[i] >> 8], 1);
    __syncthreads();
    for (int i = threadIdx.x; i < NBUCKET; i += 256)
        cur[i] = h[i] ? atomicAdd(&bfill[i], h[i]) : 0;
    __syncthreads();
    for (int i = c0 + threadIdx.x; i < c1; i += 256) {
        int d = dst[i];
        int bkt = d >> 8;
        int pos = atomicAdd(&cur[bkt], 1);
        entries[pos] = (unsigned int)src[i] | ((unsigned int)(d & 255) << 17);
    }
}

// p4x: per-bucket histogram+scan -> row_ptr, dis, col; ALSO converts x -> fp8*dis
__global__ __launch_bounds__(256) void k_p4x(const unsigned int* __restrict__ entries,
                                             const int* __restrict__ bbase,
                                             int* __restrict__ row_ptr,
                                             float* __restrict__ dis,
                                             int* __restrict__ col,
                                             const float4* __restrict__ x4,
                                             uint2* __restrict__ xb2, int N) {
    __shared__ int cnt[256];
    __shared__ int cur[256];
    __shared__ int sc[256];
    __shared__ float sdis[256];
    int b = blockIdx.x;
    int e0 = bbase[b], e1 = bbase[b + 1];
    int t = threadIdx.x;
    cnt[t] = 0; __syncthreads();
    for (int i = e0 + t; i < e1; i += 256)
        atomicAdd(&cnt[(entries[i] >> 17) & 255], 1);
    __syncthreads();
    int v = cnt[t];
    sc[t] = v; __syncthreads();
    for (int off = 1; off < 256; off <<= 1) {
        int x = (t >= off) ? sc[t - off] : 0;
        __syncthreads();
        sc[t] += x;
        __syncthreads();
    }
    int ex = sc[t] - v;
    int n = (b << 8) + t;
    float dv = rsqrtf((float)(v + 1));
    if (n <= N) row_ptr[n] = e0 + ex;
    if (n < N) dis[n] = dv;
    sdis[t] = dv;
    cur[t] = e0 + ex;
    __syncthreads();
    for (int i = e0 + t; i < e1; i += 256) {
        unsigned int en = entries[i];
        int pos = atomicAdd(&cur[(en >> 17) & 255], 1);
        col[pos] = (int)(en & 0x1FFFF);
    }
    // x -> fp8 (scaled by dis), 256 nodes x 64 dims
    for (int idx = t; idx < 256 * 8; idx += 256) {
        int node = idx >> 3, k = idx & 7;
        int gn = (b << 8) + node;
        if (gn < N) {
            float s = sdis[node];
            float4 A = x4[gn * 16 + 2 * k];
            float4 B = x4[gn * 16 + 2 * k + 1];
            uint2 u;
            u.x = pk4fp8(A.x * s, A.y * s, A.z * s, A.w * s);
            u.y = pk4fp8(B.x * s, B.y * s, B.z * s, B.w * s);
            xb2[gn * 8 + k] = u;
        }
    }
}

// ---------------- fused layer 1: slot-per-node fp8 gather -> LDS bf16 ->
//                  wave-local MFMA 64->128 (+b1, relu, *dis) -> h1 fp8 -------
__global__ __launch_bounds__(256) void k_l1f(
    const uint4* __restrict__ xb4, const int* __restrict__ row_ptr,
    const int* __restrict__ col, const float* __restrict__ dis,
    const uint4* __restrict__ Wp, const float* __restrict__ b1,
    unsigned int* __restrict__ h1u, int N) {
    __shared__ unsigned short lds[4][16][72];   // 144 B rows (16-aligned, 4-bank skew)
    const int tid = threadIdx.x, lane = tid & 63, wave = tid >> 6;
    const int slot = lane >> 2, seg = lane & 3;
    const int n = blockIdx.x * 64 + wave * 16 + slot;
    float a[16];
    #pragma unroll
    for (int q = 0; q < 16; q++) a[q] = 0.f;
    if (n < N) {
        int b = row_ptr[n], e = row_ptr[n + 1];
        acc16(xb4[n * 4 + seg], a);            // self-loop
        int i = b;
        for (; i + 4 <= e; i += 4) {
            int c0 = col[i], c1 = col[i + 1], c2 = col[i + 2], c3 = col[i + 3];
            uint4 u0 = xb4[c0 * 4 + seg], u1 = xb4[c1 * 4 + seg];
            uint4 u2 = xb4[c2 * 4 + seg], u3 = xb4[c3 * 4 + seg];
            acc16(u0, a); acc16(u1, a); acc16(u2, a); acc16(u3, a);
        }
        for (; i < e; i++) acc16(xb4[col[i] * 4 + seg], a);
        float s = dis[n];
        #pragma unroll
        for (int q = 0; q < 16; q++) a[q] *= s;
    }
    uint4 u0, u1;
    u0.x = pk2b(a[0],  a[1]);  u0.y = pk2b(a[2],  a[3]);
    u0.z = pk2b(a[4],  a[5]);  u0.w = pk2b(a[6],  a[7]);
    u1.x = pk2b(a[8],  a[9]);  u1.y = pk2b(a[10], a[11]);
    u1.z = pk2b(a[12], a[13]); u1.w = pk2b(a[14], a[15]);
    *(uint4*)&lds[wave][slot][seg * 16]     = u0;
    *(uint4*)&lds[wave][slot][seg * 16 + 8] = u1;
    __syncthreads();
    // MFMA phase: wave-local, 16 nodes
    const int quad = lane >> 4, l16 = lane & 15;
    const int node = blockIdx.x * 64 + wave * 16 + l16;
    const bool valid = node < N;
    bf16x8 bfrag[2];
    #pragma unroll
    for (int kt = 0; kt < 2; kt++)
        bfrag[kt] = *(bf16x8*)&lds[wave][l16][kt * 32 + quad * 8];
    const float s2 = valid ? dis[node] : 0.f;
    #pragma unroll
    for (int ct = 0; ct < 8; ct++) {
        f32x4 c = {0.f, 0.f, 0.f, 0.f};
        #pragma unroll
        for (int kt = 0; kt < 2; kt++) {
            uint4 wu = Wp[(kt * 4 + quad) * 128 + ct * 16 + l16];
            c = __builtin_amdgcn_mfma_f32_16x16x32_bf16(*(bf16x8*)&wu, bfrag[kt], c, 0, 0, 0);
        }
        if (valid) {
            const int chb = ct * 16 + quad * 4;
            float r0 = fmaxf(c[0] + b1[chb + 0], 0.f) * s2;
            float r1 = fmaxf(c[1] + b1[chb + 1], 0.f) * s2;
            float r2 = fmaxf(c[2] + b1[chb + 2], 0.f) * s2;
            float r3 = fmaxf(c[3] + b1[chb + 3], 0.f) * s2;
            h1u[(size_t)node * 32 + ct * 4 + quad] = pk4fp8(r0, r1, r2, r3);
        }
    }
}

// ---------------- layer-2 aggregation (unchanged topology) ------------------
// D=128 fp8: 8-lane slot owns one node; lane holds 16 dims. bf16 out [N,128].
__global__ __launch_bounds__(256) void k_agg128s(
    const uint4* __restrict__ g4, const int* __restrict__ row_ptr,
    const int* __restrict__ col, const float* __restrict__ dis,
    uint4* __restrict__ outb, int N) {
    int tid = threadIdx.x;
    int lane = tid & 63, wave = tid >> 6;
    int slot = lane >> 3, seg = lane & 7;
    int n = blockIdx.x * 32 + wave * 8 + slot;
    if (n >= N) return;
    int b = row_ptr[n], e = row_ptr[n + 1];
    float a[16];
    #pragma unroll
    for (int q = 0; q < 16; q++) a[q] = 0.f;
    acc16(g4[n * 8 + seg], a);                 // self-loop
    int i = b;
    for (; i + 4 <= e; i += 4) {
        int c0 = col[i], c1 = col[i + 1], c2 = col[i + 2], c3 = col[i + 3];
        uint4 u0 = g4[c0 * 8 + seg], u1 = g4[c1 * 8 + seg];
        uint4 u2 = g4[c2 * 8 + seg], u3 = g4[c3 * 8 + seg];
        acc16(u0, a); acc16(u1, a); acc16(u2, a); acc16(u3, a);
    }
    for (; i < e; i++) acc16(g4[col[i] * 8 + seg], a);
    float s = dis[n];
    uint4 u0, u1;
    u0.x = pk2b(s*a[0],  s*a[1]);  u0.y = pk2b(s*a[2],  s*a[3]);
    u0.z = pk2b(s*a[4],  s*a[5]);  u0.w = pk2b(s*a[6],  s*a[7]);
    u1.x = pk2b(s*a[8],  s*a[9]);  u1.y = pk2b(s*a[10], s*a[11]);
    u1.z = pk2b(s*a[12], s*a[13]); u1.w = pk2b(s*a[14], s*a[15]);
    outb[n * 16 + seg * 2]     = u0;           // row = 128 bf16 = 16 uint4
    outb[n * 16 + seg * 2 + 1] = u1;
}

// ---------------- fused mm2+mm3: MFMA 128->128 (+b2,relu,*dis) -> LDS bf16
//                  -> wave-local MFMA 128->64 -> g3 fp8 ----------------------
__global__ __launch_bounds__(256) void k_mm23(
    const uint4* __restrict__ Xb,      // bf16 [N,128] (agg2 out)
    const uint4* __restrict__ Wp2, const uint4* __restrict__ Wp3,
    const float* __restrict__ b2, const float* __restrict__ dis,
    unsigned int* __restrict__ g3u, int N) {
    __shared__ unsigned short lds[4][16][136];  // 272 B rows (16-aligned, 4-bank skew)
    const int tid = threadIdx.x, lane = tid & 63, wave = tid >> 6;
    const int quad = lane >> 4, l16 = lane & 15;
    const int node = blockIdx.x * 64 + wave * 16 + l16;
    const bool valid = node < N;
    const int nc = valid ? node : (N - 1);
    bf16x8 bfrag[4];
    const uint4* xrow = Xb + (size_t)nc * 16;
    #pragma unroll
    for (int kt = 0; kt < 4; kt++) {
        uint4 u = xrow[kt * 4 + quad];
        bfrag[kt] = *(bf16x8*)&u;
    }
    const float s = valid ? dis[node] : 0.f;
    #pragma unroll
    for (int ct = 0; ct < 8; ct++) {
        f32x4 c = {0.f, 0.f, 0.f, 0.f};
        #pragma unroll
        for (int kt = 0; kt < 4; kt++) {
            uint4 wu = Wp2[(kt * 4 + quad) * 128 + ct * 16 + l16];
            c = __builtin_amdgcn_mfma_f32_16x16x32_bf16(*(bf16x8*)&wu, bfrag[kt], c, 0, 0, 0);
        }
        const int chb = ct * 16 + quad * 4;
        float r0 = fmaxf(c[0] + b2[chb + 0], 0.f) * s;
        float r1 = fmaxf(c[1] + b2[chb + 1], 0.f) * s;
        float r2 = fmaxf(c[2] + b2[chb + 2], 0.f) * s;
        float r3 = fmaxf(c[3] + b2[chb + 3], 0.f) * s;
        uint2 u; u.x = pk2b(r0, r1); u.y = pk2b(r2, r3);
        *(uint2*)&lds[wave][l16][chb] = u;     // byte off = 2*chb, 8-aligned
    }
    __syncthreads();
    bf16x8 b2frag[4];
    #pragma unroll
    for (int kt = 0; kt < 4; kt++)
        b2frag[kt] = *(bf16x8*)&lds[wave][l16][kt * 32 + quad * 8];
    #pragma unroll
    for (int ct = 0; ct < 4; ct++) {
        f32x4 c = {0.f, 0.f, 0.f, 0.f};
        #pragma unroll
        for (int kt = 0; kt < 4; kt++) {
            uint4 wu = Wp3[(kt * 4 + quad) * 64 + ct * 16 + l16];
            c = __builtin_amdgcn_mfma_f32_16x16x32_bf16(*(bf16x8*)&wu, b2frag[kt], c, 0, 0, 0);
        }
        if (valid)
            g3u[(size_t)node * 16 + ct * 4 + quad] = pk4fp8(c[0], c[1], c[2], c[3]);
    }
}

// L3: slot-per-node aggregate (fp8) + relu(+b3) + pool. One shuffle tree/wave.
__global__ __launch_bounds__(256) void k_aggpools(
    const uint4* __restrict__ g4, const int* __restrict__ row_ptr,
    const int* __restrict__ col, const float* __restrict__ dis,
    const float* __restrict__ b3, float* __restrict__ partial, int N) {
    int tid = threadIdx.x;
    int lane = tid & 63, wave = tid >> 6;
    int slot = lane >> 2, seg = lane & 3;
    int n = blockIdx.x * 64 + wave * 16 + slot;
    float ap[16];
    #pragma unroll
    for (int j = 0; j < 16; j++) ap[j] = 0.f;
    if (n < N) {
        int b = row_ptr[n], e = row_ptr[n + 1];
        float a[16];
        #pragma unroll
        for (int q = 0; q < 16; q++) a[q] = 0.f;
        acc16(g4[n * 4 + seg], a);
        int i = b;
        for (; i + 4 <= e; i += 4) {
            int c0 = col[i], c1 = col[i + 1], c2 = col[i + 2], c3 = col[i + 3];
            uint4 u0 = g4[c0 * 4 + seg], u1 = g4[c1 * 4 + seg];
            uint4 u2 = g4[c2 * 4 + seg], u3 = g4[c3 * 4 + seg];
            acc16(u0, a); acc16(u1, a); acc16(u2, a); acc16(u3, a);
        }
        for (; i < e; i++) acc16(g4[col[i] * 4 + seg], a);
        float s = dis[n];
        #pragma unroll
        for (int j = 0; j < 16; j++)
            ap[j] = fmaxf(s * a[j] + b3[seg * 16 + j], 0.f);
    }
    #pragma unroll
    for (int j = 0; j < 16; j++) {
        ap[j] += __shfl_xor(ap[j], 4);
        ap[j] += __shfl_xor(ap[j], 8);
        ap[j] += __shfl_xor(ap[j], 16);
        ap[j] += __shfl_xor(ap[j], 32);
    }
    __shared__ float red[4][64];
    if (slot == 0) {
        #pragma unroll
        for (int j = 0; j < 16; j++) red[wave][seg * 16 + j] = ap[j];
    }
    __syncthreads();
    if (tid < 64)
        partial[blockIdx.x * 64 + tid] =
            red[0][tid] + red[1][tid] + red[2][tid] + red[3][tid];
}

// stage-1 partial reduction: block b reduces 16 rows of partial -> partial2[b][64]
__global__ __launch_bounds__(256) void k_red(
    const float* __restrict__ partial, float* __restrict__ partial2, int NB) {
    int blk = blockIdx.x;
    int t = threadIdx.x;
    int lane = t & 63, grp = t >> 6;
    int start = blk * 16;
    int end = min(NB, start + 16);
    float s = 0.f;
    for (int b = start + grp; b < end; b += 4) s += partial[b * 64 + lane];
    __shared__ float red[256];
    red[t] = s; __syncthreads();
    if (t < 64)
        partial2[blk * 64 + t] = red[t] + red[t + 64] + red[t + 128] + red[t + 192];
}

// reduce partial2 -> mean pool -> fc(relu) -> fc -> softmax -> out[2]
__global__ __launch_bounds__(256) void k_head(
    const float* __restrict__ partial, const float* __restrict__ Wc1,
    const float* __restrict__ bc1, const float* __restrict__ Wc2,
    const float* __restrict__ bc2, float* __restrict__ out, int NB, float invN) {
    __shared__ float red[256];
    __shared__ float pooled[64];
    __shared__ float z[32];
    __shared__ float lg[2];
    int t = threadIdx.x;
    int lane = t & 63, grp = t >> 6;
    float s = 0.f;
    for (int b = grp; b < NB; b += 4) s += partial[b * 64 + lane];
    red[t] = s; __syncthreads();
    if (t < 64) pooled[t] = (red[t] + red[t + 64] + red[t + 128] + red[t + 192]) * invN;
    __syncthreads();
    if (t < 32) {
        float a = bc1[t];
        for (int l = 0; l < 64; l++) a += pooled[l] * Wc1[l * 32 + t];
        z[t] = fmaxf(a, 0.f);
    }
    __syncthreads();
    if (t < 2) {
        float a = bc2[t];
        for (int j = 0; j < 32; j++) a += z[j] * Wc2[j * 2 + t];
        lg[t] = a;
    }
    __syncthreads();
    if (t == 0) {
        float m = fmaxf(lg[0], lg[1]);
        float e0 = __expf(lg[0] - m), e1 = __expf(lg[1] - m);
        float inv = 1.f / (e0 + e1);
        out[0] = e0 * inv;
        out[1] = e1 * inv;
    }
}

// ---------------- launch ----------------

extern "C" void kernel_launch(void* const* d_in, const int* in_sizes, int n_in,
                              void* d_out, int out_size, void* d_ws, size_t ws_size,
                              hipStream_t stream) {
    (void)in_sizes; (void)n_in; (void)out_size; (void)ws_size;
    const int N = NN, E = NE;

    const float* x   = (const float*)d_in[0];
    const int*   ei  = (const int*)d_in[1];
    const int*   srcp = ei;
    const int*   dstp = ei + E;
    const float* W1 = (const float*)d_in[2];
    const float* b1 = (const float*)d_in[3];
    const float* W2 = (const float*)d_in[4];
    const float* b2 = (const float*)d_in[5];
    const float* W3 = (const float*)d_in[6];
    const float* b3 = (const float*)d_in[7];
    const float* Wc1 = (const float*)d_in[8];
    const float* bc1 = (const float*)d_in[9];
    const float* Wc2 = (const float*)d_in[10];
    const float* bc2 = (const float*)d_in[11];
    float* out = (float*)d_out;

    char* base = (char*)d_ws;
    size_t off = 0;
    auto carve = [&](size_t bytes) -> char* {
        char* p = base + off;
        off = (off + bytes + 255) & ~(size_t)255;
        return p;
    };
    int*   bcnt    = (int*)carve((size_t)NBUCKET * 4);
    int*   bbase   = (int*)carve((size_t)(NBUCKET + 1) * 4);
    int*   bfill   = (int*)carve((size_t)NBUCKET * 4);
    int*   row_ptr = (int*)carve((size_t)(N + 1) * 4);
    int*   col     = (int*)carve((size_t)E * 4);
    float* dis     = (float*)carve((size_t)N * 4);
    float* partial = (float*)carve((size_t)1600 * 64 * 4);
    float* partial2= (float*)carve((size_t)128 * 64 * 4);
    uint4* Wp      = (uint4*)carve((size_t)4096 * 16);              // packed bf16 weights
    unsigned int* entries = (unsigned int*)carve((size_t)E * 4);
    unsigned int* xb      = (unsigned int*)carve((size_t)N * 64);   // fp8 [N,64]
    unsigned int* h1u     = (unsigned int*)carve((size_t)N * 128);  // fp8 [N,128]
    unsigned int* g3u     = (unsigned int*)carve((size_t)N * 64);   // fp8 [N,64]
    uint4*        bufB    = (uint4*)carve((size_t)N * 128 * 2);     // bf16 agg2 out

    // ---- init (bcnt zero + weight swizzle) + CSR build + x->fp8 ----
    k_init<<<18, 256, 0, stream>>>(W1, W2, W3, Wp, bcnt);
    k_p1<<<512, 256, 0, stream>>>(dstp, bcnt, E);
    k_scanb<<<1, 512, 0, stream>>>(bcnt, bbase, bfill);
    k_p2<<<(E + CHUNK - 1) / CHUNK, 256, 0, stream>>>(srcp, dstp, bfill, entries, E);
    k_p4x<<<NBUCKET, 256, 0, stream>>>(entries, bbase, row_ptr, dis, col,
                                       (const float4*)x, (uint2*)xb, N);

    const int NB64 = (N + 63) / 64;    // 1563
    const int NB32 = (N + 31) / 32;    // 3125

    // ---- layer 1 (fused gather+MFMA) ----
    k_l1f<<<NB64, 256, 0, stream>>>((const uint4*)xb, row_ptr, col, dis, Wp, b1, h1u, N);

    // ---- layer 2 aggregate, then fused mm2+mm3 ----
    k_agg128s<<<NB32, 256, 0, stream>>>((const uint4*)h1u, row_ptr, col, dis, bufB, N);
    k_mm23<<<NB64, 256, 0, stream>>>(bufB, Wp + 1024, Wp + 3072, b2, dis, g3u, N);

    // ---- layer 3 aggregate + pool ----
    k_aggpools<<<NB64, 256, 0, stream>>>((const uint4*)g3u, row_ptr, col, dis, b3, partial, N);

    // ---- two-stage pooled reduction + head ----
    const int NRED = (NB64 + 15) / 16;   // 98
    k_red<<<NRED, 256, 0, stream>>>(partial, partial2, NB64);
    k_head<<<1, 256, 0, stream>>>(partial2, Wc1, bc1, Wc2, bc2, out, NRED, 1.0f / (float)N);
}